// Round 2
// baseline (2308.474 us; speedup 1.0000x reference)
//
#include <hip/hip_runtime.h>
#include <hip/hip_bf16.h>
#include <math.h>

#define BB 16
#define HH 56
#define WW 56
#define CC0 192
#define NHH 6
#define HDD 32
#define NPOS (HH*WW)       // 3136
#define MROWS (BB*NPOS)    // 50176
#define C4 (4*CC0)         // 768

typedef __hip_bfloat16 bf16;

__device__ __forceinline__ float b2f(bf16 v){ return __bfloat162float(v); }
__device__ __forceinline__ bf16 f2b(float v){ return __float2bfloat16(v); }
__device__ __forceinline__ float ldf(float v){ return v; }
__device__ __forceinline__ float ldf(bf16 v){ return __bfloat162float(v); }

// ---------------- depthwise 3x3 conv ----------------
// MODE 0: out(f32) = in + (conv+bias)      (cpe1/cpe2 residual)
// MODE 1: out(f32) = silu(conv+bias)       (dwc)
// MODE 2: out(f32) += (conv+bias)          (lepe accumulate)
// MODE 3: out(bf16) = conv+bias            (mdw)
template<typename TIN, typename TOUT, int CC, int MODE>
__global__ __launch_bounds__(CC) void dwconv_kernel(const TIN* __restrict__ in,
    const float* __restrict__ w, const float* __restrict__ bias, TOUT* __restrict__ out){
  int pos = blockIdx.x;
  int c = threadIdx.x;
  int b = pos / NPOS; int ij = pos % NPOS; int i = ij / WW; int j = ij % WW;
  float acc = bias[c];
  #pragma unroll
  for (int di = 0; di < 3; ++di){
    int ii = i + di - 1;
    if (ii < 0 || ii >= HH) continue;
    #pragma unroll
    for (int dj = 0; dj < 3; ++dj){
      int jj = j + dj - 1;
      if (jj < 0 || jj >= WW) continue;
      float xv = ldf(in[((size_t)(b*NPOS) + (ii*WW + jj))*CC + c]);
      acc += xv * w[(di*3 + dj)*CC + c];
    }
  }
  size_t idx = (size_t)pos*CC + c;
  if constexpr (MODE == 0) out[idx] = ldf(in[idx]) + acc;
  else if constexpr (MODE == 1) out[idx] = acc / (1.f + expf(-acc));
  else if constexpr (MODE == 2) out[idx] = out[idx] + acc;
  else out[idx] = f2b(acc);
}

// ---------------- LayerNorm over C=192 (fp32 in/out) ----------------
__global__ __launch_bounds__(64) void ln192_kernel(const float* __restrict__ x,
    const float* __restrict__ g, const float* __restrict__ bb, float* __restrict__ out){
  int row = blockIdx.x; int t = threadIdx.x;
  const float* xr = x + (size_t)row*CC0;
  float v0 = xr[t], v1 = xr[t+64], v2 = xr[t+128];
  float s = v0+v1+v2;
  float q = v0*v0+v1*v1+v2*v2;
  #pragma unroll
  for (int m = 1; m < 64; m <<= 1){ s += __shfl_xor(s, m, 64); q += __shfl_xor(q, m, 64); }
  float mean = s * (1.f/CC0);
  float rstd = rsqrtf(q * (1.f/CC0) - mean*mean + 1e-5f);
  float* orow = out + (size_t)row*CC0;
  orow[t]     = (v0-mean)*rstd*g[t]     + bb[t];
  orow[t+64]  = (v1-mean)*rstd*g[t+64]  + bb[t+64];
  orow[t+128] = (v2-mean)*rstd*g[t+128] + bb[t+128];
}

// ---------------- GEMM: [MROWS,K] @ [K,NOUT] + bias, fused epilogues ----------------
// ALOAD: 0 = fp32, 1 = fp32 a0*a1 product, 2 = gelu(bf16)
// EPI:   0 = silu->f32, 1 = +bias->f32, 2 = elu+1 split q/k ->f32,
//        3 = +shortcut ->f32, 4 = ->bf16, 5 = +resid(f32) ->f32
template<int K, int NOUT, int ROWS, int ALOAD, int EPI>
__global__ __launch_bounds__(NOUT) void gemm_kernel(
    const void* __restrict__ a0v, const void* __restrict__ a1v,
    const float* __restrict__ w, const float* __restrict__ bias,
    const float* __restrict__ addf, void* __restrict__ out0, void* __restrict__ out1){
  __shared__ float As[ROWS][K];
  int tid = threadIdx.x;
  size_t base_row = (size_t)blockIdx.x * ROWS;
  for (int idx = tid; idx < ROWS*K; idx += NOUT){
    int r = idx / K, kk = idx % K;
    size_t off = (base_row + r)*(size_t)K + kk;
    float v;
    if constexpr (ALOAD == 0) v = ((const float*)a0v)[off];
    else if constexpr (ALOAD == 1) v = ((const float*)a0v)[off] * ((const float*)a1v)[off];
    else { float xv = b2f(((const bf16*)a0v)[off]); v = 0.5f*xv*(1.f + erff(xv*0.70710678118f)); }
    As[r][kk] = v;
  }
  __syncthreads();
  int col = tid;
  float acc[ROWS];
  #pragma unroll
  for (int r = 0; r < ROWS; ++r) acc[r] = 0.f;
  for (int kk = 0; kk < K; ++kk){
    float wv = w[(size_t)kk*NOUT + col];
    #pragma unroll
    for (int r = 0; r < ROWS; ++r) acc[r] += As[r][kk] * wv;
  }
  float bv = bias[col];
  #pragma unroll
  for (int r = 0; r < ROWS; ++r){
    size_t row = base_row + r;
    float v = acc[r] + bv;
    if constexpr (EPI == 0) ((float*)out0)[row*NOUT + col] = v / (1.f + expf(-v));
    else if constexpr (EPI == 1) ((float*)out0)[row*NOUT + col] = v;
    else if constexpr (EPI == 2) {
      float rv = (v > 0.f) ? (v + 1.f) : expf(v);
      if (col < NOUT/2) ((float*)out0)[row*(NOUT/2) + col] = rv;
      else              ((float*)out1)[row*(NOUT/2) + (col - NOUT/2)] = rv;
    }
    else if constexpr (EPI == 3) ((float*)out0)[row*NOUT + col] = addf[row*NOUT + col] + v;
    else if constexpr (EPI == 4) ((bf16*)out0)[row*NOUT + col] = f2b(v);
    else ((float*)out0)[row*NOUT + col] = addf[row*NOUT + col] + v;
  }
}

// ---------------- RoPE tables (H,W,96) ----------------
__global__ void rope_tables_kernel(float* __restrict__ cosT, float* __restrict__ sinT){
  int idx = blockIdx.x*256 + threadIdx.x;
  if (idx >= NPOS*96) return;
  int t = idx % 96; int ij = idx / 96; int i = ij / WW; int j = ij % WW;
  int kk = (t < 48) ? t : (t - 48);
  float th = expf(-(float)kk * 0.19188209108283716f);  // 10000^(-k/48)
  float pos = (t < 48) ? (float)i : (float)j;
  float ang = pos * th;
  cosT[idx] = cosf(ang);
  sinT[idx] = sinf(ang);
}

// ---------------- kmean: mean over N of k ----------------
__global__ __launch_bounds__(CC0) void kmean_kernel(const float* __restrict__ k, float* __restrict__ kmean){
  int b = blockIdx.x / 7; int chunk = blockIdx.x % 7; int c = threadIdx.x;
  const float* kp = k + ((size_t)b*NPOS + (size_t)chunk*448)*CC0 + c;
  float s = 0.f;
  for (int r = 0; r < 448; ++r) s += kp[(size_t)r*CC0];
  atomicAdd(&kmean[b*CC0 + c], s * (1.f/NPOS));
}

// ---------------- kv = sum_n rope(k)[d] * v[e] / N ----------------
__global__ __launch_bounds__(256) void kv_kernel(const float* __restrict__ kbuf,
    const float* __restrict__ hbuf, const float* __restrict__ cosT,
    const float* __restrict__ sinT, float* __restrict__ kv){
  int bi = blockIdx.x;
  int chunk = bi % 14; bi /= 14;
  int h = bi % NHH; int b = bi / NHH;
  int tid = threadIdx.x;
  int r8 = tid >> 5, lane = tid & 31;
  __shared__ float krs[8][32];
  __shared__ float vvs[8][32];
  int d = tid >> 3; int ebase = (tid & 7) * 4;
  float a0 = 0.f, a1 = 0.f, a2 = 0.f, a3 = 0.f;
  int c = h*HDD + lane;
  int t = c >> 1;
  bool odd = (lane & 1);
  for (int step = 0; step < 28; ++step){
    int n = chunk*224 + step*8 + r8;
    size_t row = (size_t)b*NPOS + n;
    float kc = kbuf[row*CC0 + c];
    float kp = kbuf[row*CC0 + (c ^ 1)];
    float cs = cosT[(size_t)n*96 + t], sn = sinT[(size_t)n*96 + t];
    krs[r8][lane] = odd ? (cs*kc + sn*kp) : (cs*kc - sn*kp);
    vvs[r8][lane] = hbuf[row*CC0 + c];
    __syncthreads();
    #pragma unroll
    for (int nn = 0; nn < 8; ++nn){
      float kk2 = krs[nn][d];
      a0 += kk2 * vvs[nn][ebase+0];
      a1 += kk2 * vvs[nn][ebase+1];
      a2 += kk2 * vvs[nn][ebase+2];
      a3 += kk2 * vvs[nn][ebase+3];
    }
    __syncthreads();
  }
  const float invN = 1.f/NPOS;
  float* kvp = kv + (((size_t)(b*NHH + h)*HDD + d)*HDD) + ebase;
  atomicAdd(kvp+0, a0*invN);
  atomicAdd(kvp+1, a1*invN);
  atomicAdd(kvp+2, a2*invN);
  atomicAdd(kvp+3, a3*invN);
}

// ---------------- fused attention: z + rope(q) + q_r@kv ----------------
__global__ __launch_bounds__(CC0) void attn_kernel(const float* __restrict__ q,
    const float* __restrict__ kmean, const float* __restrict__ kv,
    const float* __restrict__ cosT, const float* __restrict__ sinT,
    float* __restrict__ out){
  int row = blockIdx.x;
  int tid = threadIdx.x;
  int b = row / NPOS; int n = row % NPOS;
  __shared__ float qs[CC0];
  __shared__ float qrs[NHH*33];
  __shared__ float zsh[NHH];
  qs[tid] = q[(size_t)row*CC0 + tid];
  __syncthreads();
  // z: per-head reduction of q . kmean (un-roped)
  float pm = qs[tid] * kmean[b*CC0 + tid];
  #pragma unroll
  for (int m = 16; m >= 1; m >>= 1) pm += __shfl_xor(pm, m, 32);
  if ((tid & 31) == 0) zsh[tid >> 5] = 1.f/(pm + 1e-6f);
  // rope(q)
  int t = tid >> 1;
  float cs = cosT[(size_t)n*96 + t], sn = sinT[(size_t)n*96 + t];
  float qr = (tid & 1) ? (cs*qs[tid] + sn*qs[tid-1]) : (cs*qs[tid] - sn*qs[tid+1]);
  int hh = tid >> 5, d = tid & 31;
  qrs[hh*33 + d] = qr;
  __syncthreads();
  const float* kvp = kv + (size_t)(b*NHH + hh)*HDD*HDD;
  float acc = 0.f;
  #pragma unroll
  for (int d2 = 0; d2 < HDD; ++d2) acc += qrs[hh*33 + d2] * kvp[d2*HDD + d];
  out[(size_t)row*CC0 + tid] = acc * zsh[hh];
}

// ---------------- LN over 768 of (a + f1), in-place into a (bf16) ----------------
__global__ __launch_bounds__(256) void lnadd768_kernel(bf16* __restrict__ a,
    const bf16* __restrict__ f1, const float* __restrict__ g, const float* __restrict__ bb){
  int row = blockIdx.x; int tid = threadIdx.x;
  size_t base = (size_t)row*C4;
  float v0 = b2f(a[base+tid])     + b2f(f1[base+tid]);
  float v1 = b2f(a[base+tid+256]) + b2f(f1[base+tid+256]);
  float v2 = b2f(a[base+tid+512]) + b2f(f1[base+tid+512]);
  float s = v0+v1+v2, q = v0*v0+v1*v1+v2*v2;
  #pragma unroll
  for (int m = 1; m < 64; m <<= 1){ s += __shfl_xor(s, m, 64); q += __shfl_xor(q, m, 64); }
  __shared__ float rs[4], rq[4];
  int wave = tid >> 6;
  if ((tid & 63) == 0){ rs[wave] = s; rq[wave] = q; }
  __syncthreads();
  float S = rs[0]+rs[1]+rs[2]+rs[3];
  float Q = rq[0]+rq[1]+rq[2]+rq[3];
  float mean = S * (1.f/C4);
  float rstd = rsqrtf(Q * (1.f/C4) - mean*mean + 1e-5f);
  a[base+tid]     = f2b((v0-mean)*rstd*g[tid]     + bb[tid]);
  a[base+tid+256] = f2b((v1-mean)*rstd*g[tid+256] + bb[tid+256]);
  a[base+tid+512] = f2b((v2-mean)*rstd*g[tid+512] + bb[tid+512]);
}

extern "C" void kernel_launch(void* const* d_in, const int* in_sizes, int n_in,
                              void* d_out, int out_size, void* d_ws, size_t ws_size,
                              hipStream_t stream){
  (void)in_sizes; (void)n_in; (void)out_size; (void)ws_size;
  const float* X      = (const float*)d_in[0];
  const float* cpe1_w = (const float*)d_in[1];
  const float* cpe1_b = (const float*)d_in[2];
  const float* n1g    = (const float*)d_in[3];
  const float* n1b    = (const float*)d_in[4];
  const float* in_w   = (const float*)d_in[5];
  const float* in_b   = (const float*)d_in[6];
  const float* actp_w = (const float*)d_in[7];
  const float* actp_b = (const float*)d_in[8];
  const float* dwc_w  = (const float*)d_in[9];
  const float* dwc_b  = (const float*)d_in[10];
  const float* qk_w   = (const float*)d_in[11];
  const float* qk_b   = (const float*)d_in[12];
  const float* lepe_w = (const float*)d_in[13];
  const float* lepe_b = (const float*)d_in[14];
  const float* outp_w = (const float*)d_in[15];
  const float* outp_b = (const float*)d_in[16];
  const float* cpe2_w = (const float*)d_in[17];
  const float* cpe2_b = (const float*)d_in[18];
  const float* n2g    = (const float*)d_in[19];
  const float* n2b    = (const float*)d_in[20];
  const float* fc1_w  = (const float*)d_in[21];
  const float* fc1_b  = (const float*)d_in[22];
  const float* mdw_w  = (const float*)d_in[23];
  const float* mdw_b  = (const float*)d_in[24];
  const float* fc2_w  = (const float*)d_in[25];
  const float* fc2_b  = (const float*)d_in[26];
  const float* mn1g   = (const float*)d_in[27];
  const float* mn1b   = (const float*)d_in[28];
  const float* mn2g   = (const float*)d_in[29];
  const float* mn2b   = (const float*)d_in[30];
  const float* mn3g   = (const float*)d_in[31];
  const float* mn3b   = (const float*)d_in[32];

  char* ws = (char*)d_ws;
  const size_t SZ1 = (size_t)MROWS*CC0*sizeof(float);  // 38,535,168 B
  float* S0 = (float*)(ws);             // x1 (shortcut) -> x3
  float* S1 = (float*)(ws + 1*SZ1);     // xn -> k -> attn -> xm
  float* S2 = (float*)(ws + 2*SZ1);     // act_res
  float* S3 = (float*)(ws + 3*SZ1);     // t -> q -> x2
  float* S4 = (float*)(ws + 4*SZ1);     // h
  bf16*  F1 = (bf16*)(ws + 2*SZ1);      // f1 bf16, spans S2+S3 (dead then)
  bf16*  DW = (bf16*)(ws + 4*SZ1);      // dw/n-chain bf16, spans S4+S5
  char* tail = ws + 6*SZ1;
  float* KMEAN = (float*)tail;                 tail += (size_t)BB*CC0*4;
  float* KV    = (float*)tail;                 tail += (size_t)BB*NHH*HDD*HDD*4;
  float* COS   = (float*)tail;                 tail += (size_t)NPOS*96*4;
  float* SIN   = (float*)tail;

  // 1. x1 = x + cpe1(x)
  dwconv_kernel<float,float,CC0,0><<<MROWS, CC0, 0, stream>>>(X, cpe1_w, cpe1_b, S0);
  rope_tables_kernel<<<(NPOS*96 + 255)/256, 256, 0, stream>>>(COS, SIN);
  // 2. xn = LN(x1)
  ln192_kernel<<<MROWS, 64, 0, stream>>>(S0, n1g, n1b, S1);
  // 3. act_res = silu(xn@actp)
  gemm_kernel<CC0,CC0,8,0,0><<<MROWS/8, CC0, 0, stream>>>(S1, nullptr, actp_w, actp_b, nullptr, S2, nullptr);
  // 4. t = xn@in_w + b
  gemm_kernel<CC0,CC0,8,0,1><<<MROWS/8, CC0, 0, stream>>>(S1, nullptr, in_w, in_b, nullptr, S3, nullptr);
  // 5. h = silu(dwc(t))
  dwconv_kernel<float,float,CC0,1><<<MROWS, CC0, 0, stream>>>(S3, dwc_w, dwc_b, S4);
  // 6. qk = h@qk_w; q->S3, k->S1 (elu+1)
  gemm_kernel<CC0,2*CC0,8,0,2><<<MROWS/8, 2*CC0, 0, stream>>>(S4, nullptr, qk_w, qk_b, nullptr, S3, S1);
  // 7. kmean, kv
  hipMemsetAsync(KMEAN, 0, (size_t)BB*CC0*4, stream);
  hipMemsetAsync(KV, 0, (size_t)BB*NHH*HDD*HDD*4, stream);
  kmean_kernel<<<BB*7, CC0, 0, stream>>>(S1, KMEAN);
  kv_kernel<<<BB*NHH*14, 256, 0, stream>>>(S1, S4, COS, SIN, KV);
  // 8. attn core -> S1
  attn_kernel<<<MROWS, CC0, 0, stream>>>(S3, KMEAN, KV, COS, SIN, S1);
  // 9. attn += lepe(h)
  dwconv_kernel<float,float,CC0,2><<<MROWS, CC0, 0, stream>>>(S4, lepe_w, lepe_b, S1);
  // 10. x2 = shortcut + (attn*act_res)@outp + b
  gemm_kernel<CC0,CC0,8,1,3><<<MROWS/8, CC0, 0, stream>>>(S1, S2, outp_w, outp_b, S0, S3, nullptr);
  // 11. x3 = x2 + cpe2(x2)
  dwconv_kernel<float,float,CC0,0><<<MROWS, CC0, 0, stream>>>(S3, cpe2_w, cpe2_b, S0);
  // 12. xm = LN(x3)
  ln192_kernel<<<MROWS, 64, 0, stream>>>(S0, n2g, n2b, S1);
  // 13. f1 = xm@fc1 + b (bf16)
  gemm_kernel<CC0,C4,8,0,4><<<MROWS/8, C4, 0, stream>>>(S1, nullptr, fc1_w, fc1_b, nullptr, F1, nullptr);
  // 14. dw = mdw(f1) (bf16)
  dwconv_kernel<bf16,bf16,C4,3><<<MROWS, C4, 0, stream>>>(F1, mdw_w, mdw_b, DW);
  // 15. n1/n2/n3 chained LNs (in-place in DW)
  lnadd768_kernel<<<MROWS, 256, 0, stream>>>(DW, F1, mn1g, mn1b);
  lnadd768_kernel<<<MROWS, 256, 0, stream>>>(DW, F1, mn2g, mn2b);
  lnadd768_kernel<<<MROWS, 256, 0, stream>>>(DW, F1, mn3g, mn3b);
  // 16. out = x3 + gelu(n3)@fc2 + b (f32)
  gemm_kernel<C4,CC0,8,2,5><<<MROWS/8, CC0, 0, stream>>>(DW, nullptr, fc2_w, fc2_b, S0, d_out, nullptr);
}

// Round 3
// 1228.218 us; speedup vs baseline: 1.8795x; 1.8795x over previous
//
#include <hip/hip_runtime.h>
#include <hip/hip_bf16.h>
#include <math.h>

#define BB 16
#define HH 56
#define WW 56
#define CC0 192
#define NHH 6
#define HDD 32
#define NPOS (HH*WW)       // 3136
#define MROWS (BB*NPOS)    // 50176
#define C4 (4*CC0)         // 768

typedef __hip_bfloat16 bf16;
typedef short short8 __attribute__((ext_vector_type(8)));
typedef short short4v __attribute__((ext_vector_type(4)));
typedef float f32x4 __attribute__((ext_vector_type(4)));

__device__ __forceinline__ float b2f(bf16 v){ return __bfloat162float(v); }
__device__ __forceinline__ bf16 f2b(float v){ return __float2bfloat16(v); }
__device__ __forceinline__ short f2s(float v){ bf16 b = __float2bfloat16(v); return *(short*)&b; }
__device__ __forceinline__ float s2f(short s){ bf16 b; *(short*)&b = s; return __bfloat162float(b); }
__device__ __forceinline__ float ldf(float v){ return v; }
__device__ __forceinline__ float ldf(bf16 v){ return __bfloat162float(v); }
__device__ __forceinline__ void stf(float* p, float v){ *p = v; }
__device__ __forceinline__ void stf(bf16* p, float v){ *p = f2b(v); }

// ---------------- depthwise 3x3 conv ----------------
// MODE 0: out = in + (conv+bias)      (cpe1/cpe2 residual)
// MODE 1: out = silu(conv+bias)       (dwc)
// MODE 2: out += (conv+bias)          (lepe accumulate, f32)
// MODE 3: out = conv+bias             (mdw)
template<typename TIN, typename TOUT, int CC, int MODE>
__global__ __launch_bounds__(CC) void dwconv_kernel(const TIN* __restrict__ in,
    const float* __restrict__ w, const float* __restrict__ bias, TOUT* __restrict__ out){
  int pos = blockIdx.x;
  int c = threadIdx.x;
  int b = pos / NPOS; int ij = pos % NPOS; int i = ij / WW; int j = ij % WW;
  float acc = bias[c];
  #pragma unroll
  for (int di = 0; di < 3; ++di){
    int ii = i + di - 1;
    if (ii < 0 || ii >= HH) continue;
    #pragma unroll
    for (int dj = 0; dj < 3; ++dj){
      int jj = j + dj - 1;
      if (jj < 0 || jj >= WW) continue;
      float xv = ldf(in[((size_t)(b*NPOS) + (ii*WW + jj))*CC + c]);
      acc += xv * w[(di*3 + dj)*CC + c];
    }
  }
  size_t idx = (size_t)pos*CC + c;
  if constexpr (MODE == 0) stf(&out[idx], ldf(in[idx]) + acc);
  else if constexpr (MODE == 1) stf(&out[idx], acc / (1.f + expf(-acc)));
  else if constexpr (MODE == 2) out[idx] = out[idx] + acc;
  else stf(&out[idx], acc);
}

// ---------------- LayerNorm over C=192 (f32 in, bf16 out) ----------------
__global__ __launch_bounds__(64) void ln192_kernel(const float* __restrict__ x,
    const float* __restrict__ g, const float* __restrict__ bb, bf16* __restrict__ out){
  int row = blockIdx.x; int t = threadIdx.x;
  const float* xr = x + (size_t)row*CC0;
  float v0 = xr[t], v1 = xr[t+64], v2 = xr[t+128];
  float s = v0+v1+v2;
  float q = v0*v0+v1*v1+v2*v2;
  #pragma unroll
  for (int m = 1; m < 64; m <<= 1){ s += __shfl_xor(s, m, 64); q += __shfl_xor(q, m, 64); }
  float mean = s * (1.f/CC0);
  float rstd = rsqrtf(q * (1.f/CC0) - mean*mean + 1e-5f);
  bf16* orow = out + (size_t)row*CC0;
  orow[t]     = f2b((v0-mean)*rstd*g[t]     + bb[t]);
  orow[t+64]  = f2b((v1-mean)*rstd*g[t+64]  + bb[t+64]);
  orow[t+128] = f2b((v2-mean)*rstd*g[t+128] + bb[t+128]);
}

// ---------------- MFMA GEMM: [MROWS,K](bf16-ish) @ [K,N](f32 w) + bias ----------------
// ALOAD: 0 = bf16 direct, 1 = f32 * bf16 product (attn * act_res)
// EPI:   0 = store bf16, 1 = silu->bf16, 2 = elu+1 split q/k ->f32,
//        3 = +addf(f32) -> f32
#define BM 256
#define BN 64
#define BK 32
#define LDA 40
template<int K, int N, int ALOAD, int EPI>
__global__ __launch_bounds__(256) void mfma_gemm(
    const void* __restrict__ a0v, const bf16* __restrict__ a1v,
    const float* __restrict__ w, const float* __restrict__ bias,
    const float* __restrict__ addf, void* __restrict__ out0, void* __restrict__ out1){
  __shared__ short As[BM*LDA];
  __shared__ short Bs[BN*LDA];
  int tid = threadIdx.x;
  int wave = tid >> 6, lane = tid & 63;
  size_t m0 = (size_t)blockIdx.x * BM;
  int n0 = blockIdx.y * BN;
  int wm = wave * 64;
  int am = lane & 15, ak = (lane >> 4) * 8;

  f32x4 acc[4][4];
  #pragma unroll
  for (int mt = 0; mt < 4; ++mt)
    #pragma unroll
    for (int nt = 0; nt < 4; ++nt)
      acc[mt][nt] = (f32x4){0.f,0.f,0.f,0.f};

  for (int k0 = 0; k0 < K; k0 += BK){
    // ---- stage A (BM x BK) ----
    if constexpr (ALOAD == 0){
      const short* A = (const short*)a0v;
      #pragma unroll
      for (int it = 0; it < 4; ++it){
        int idx = it*256 + tid;           // 1024 octets of 8
        int row = idx >> 2; int ko = (idx & 3) * 8;
        short8 v = *(const short8*)(A + (m0 + row)*(size_t)K + k0 + ko);
        *(short8*)&As[row*LDA + ko] = v;
      }
    } else {
      const float* A = (const float*)a0v;
      #pragma unroll
      for (int it = 0; it < 8; ++it){
        int idx = it*256 + tid;           // 2048 quads of 4
        int row = idx >> 3; int kq = (idx & 7) * 4;
        size_t off = (m0 + row)*(size_t)K + k0 + kq;
        f32x4 v = *(const f32x4*)(A + off);
        short4v sv = *(const short4v*)((const short*)a1v + off);
        short4v o;
        o.x = f2s(v.x * s2f(sv.x)); o.y = f2s(v.y * s2f(sv.y));
        o.z = f2s(v.z * s2f(sv.z)); o.w = f2s(v.w * s2f(sv.w));
        *(short4v*)&As[row*LDA + kq] = o;
      }
    }
    // ---- stage B transposed: Bs[n][k] (BK x BN source) ----
    #pragma unroll
    for (int it = 0; it < 8; ++it){
      int idx = it*256 + tid;             // 2048 elements
      int kk = idx >> 6, nn = idx & 63;
      float wv = w[(size_t)(k0 + kk)*N + n0 + nn];
      Bs[nn*LDA + kk] = f2s(wv);
    }
    __syncthreads();
    // ---- fragments + MFMA ----
    short8 af[4], bfr[4];
    #pragma unroll
    for (int mt = 0; mt < 4; ++mt) af[mt] = *(short8*)&As[(wm + mt*16 + am)*LDA + ak];
    #pragma unroll
    for (int nt = 0; nt < 4; ++nt) bfr[nt] = *(short8*)&Bs[(nt*16 + am)*LDA + ak];
    #pragma unroll
    for (int mt = 0; mt < 4; ++mt)
      #pragma unroll
      for (int nt = 0; nt < 4; ++nt)
        acc[mt][nt] = __builtin_amdgcn_mfma_f32_16x16x32_bf16(af[mt], bfr[nt], acc[mt][nt], 0, 0, 0);
    __syncthreads();
  }

  // ---- epilogue ----
  int cn = lane & 15;
  int cr = (lane >> 4) * 4;
  #pragma unroll
  for (int mt = 0; mt < 4; ++mt){
    #pragma unroll
    for (int nt = 0; nt < 4; ++nt){
      int gn = n0 + nt*16 + cn;
      float bv = bias[gn];
      #pragma unroll
      for (int r = 0; r < 4; ++r){
        size_t gm = m0 + wm + mt*16 + cr + r;
        float v = acc[mt][nt][r] + bv;
        if constexpr (EPI == 0){
          ((bf16*)out0)[gm*N + gn] = f2b(v);
        } else if constexpr (EPI == 1){
          ((bf16*)out0)[gm*N + gn] = f2b(v / (1.f + expf(-v)));
        } else if constexpr (EPI == 2){
          float rv = (v > 0.f) ? (v + 1.f) : expf(v);
          if (n0 < CC0) ((float*)out0)[gm*CC0 + gn] = rv;
          else          ((float*)out1)[gm*CC0 + (gn - CC0)] = rv;
        } else {
          ((float*)out0)[gm*N + gn] = addf[gm*N + gn] + v;
        }
      }
    }
  }
}

// ---------------- RoPE tables (H,W,96) ----------------
__global__ void rope_tables_kernel(float* __restrict__ cosT, float* __restrict__ sinT){
  int idx = blockIdx.x*256 + threadIdx.x;
  if (idx >= NPOS*96) return;
  int t = idx % 96; int ij = idx / 96; int i = ij / WW; int j = ij % WW;
  int kk = (t < 48) ? t : (t - 48);
  float th = expf(-(float)kk * 0.19188209108283716f);  // 10000^(-k/48)
  float pos = (t < 48) ? (float)i : (float)j;
  float ang = pos * th;
  cosT[idx] = cosf(ang);
  sinT[idx] = sinf(ang);
}

// ---------------- kmean: mean over N of k ----------------
__global__ __launch_bounds__(CC0) void kmean_kernel(const float* __restrict__ k, float* __restrict__ kmean){
  int b = blockIdx.x / 7; int chunk = blockIdx.x % 7; int c = threadIdx.x;
  const float* kp = k + ((size_t)b*NPOS + (size_t)chunk*448)*CC0 + c;
  float s = 0.f;
  for (int r = 0; r < 448; ++r) s += kp[(size_t)r*CC0];
  atomicAdd(&kmean[b*CC0 + c], s * (1.f/NPOS));
}

// ---------------- kv = sum_n rope(k)[d] * v[e] / N ----------------
__global__ __launch_bounds__(256) void kv_kernel(const float* __restrict__ kbuf,
    const bf16* __restrict__ hbuf, const float* __restrict__ cosT,
    const float* __restrict__ sinT, float* __restrict__ kv){
  int bi = blockIdx.x;
  int chunk = bi % 14; bi /= 14;
  int h = bi % NHH; int b = bi / NHH;
  int tid = threadIdx.x;
  int r8 = tid >> 5, lane = tid & 31;
  __shared__ float krs[8][32];
  __shared__ float vvs[8][32];
  int d = tid >> 3; int ebase = (tid & 7) * 4;
  float a0 = 0.f, a1 = 0.f, a2 = 0.f, a3 = 0.f;
  int c = h*HDD + lane;
  int t = c >> 1;
  bool odd = (lane & 1);
  for (int step = 0; step < 28; ++step){
    int n = chunk*224 + step*8 + r8;
    size_t row = (size_t)b*NPOS + n;
    float kc = kbuf[row*CC0 + c];
    float kp = kbuf[row*CC0 + (c ^ 1)];
    float cs = cosT[(size_t)n*96 + t], sn = sinT[(size_t)n*96 + t];
    krs[r8][lane] = odd ? (cs*kc + sn*kp) : (cs*kc - sn*kp);
    vvs[r8][lane] = b2f(hbuf[row*CC0 + c]);
    __syncthreads();
    #pragma unroll
    for (int nn = 0; nn < 8; ++nn){
      float kk2 = krs[nn][d];
      a0 += kk2 * vvs[nn][ebase+0];
      a1 += kk2 * vvs[nn][ebase+1];
      a2 += kk2 * vvs[nn][ebase+2];
      a3 += kk2 * vvs[nn][ebase+3];
    }
    __syncthreads();
  }
  const float invN = 1.f/NPOS;
  float* kvp = kv + (((size_t)(b*NHH + h)*HDD + d)*HDD) + ebase;
  atomicAdd(kvp+0, a0*invN);
  atomicAdd(kvp+1, a1*invN);
  atomicAdd(kvp+2, a2*invN);
  atomicAdd(kvp+3, a3*invN);
}

// ---------------- fused attention: z + rope(q) + q_r@kv ----------------
__global__ __launch_bounds__(CC0) void attn_kernel(const float* __restrict__ q,
    const float* __restrict__ kmean, const float* __restrict__ kv,
    const float* __restrict__ cosT, const float* __restrict__ sinT,
    float* __restrict__ out){
  int row = blockIdx.x;
  int tid = threadIdx.x;
  int b = row / NPOS; int n = row % NPOS;
  __shared__ float qs[CC0];
  __shared__ float qrs[NHH*33];
  __shared__ float zsh[NHH];
  qs[tid] = q[(size_t)row*CC0 + tid];
  __syncthreads();
  float pm = qs[tid] * kmean[b*CC0 + tid];
  #pragma unroll
  for (int m = 16; m >= 1; m >>= 1) pm += __shfl_xor(pm, m, 32);
  if ((tid & 31) == 0) zsh[tid >> 5] = 1.f/(pm + 1e-6f);
  int t = tid >> 1;
  float cs = cosT[(size_t)n*96 + t], sn = sinT[(size_t)n*96 + t];
  float qr = (tid & 1) ? (cs*qs[tid] + sn*qs[tid-1]) : (cs*qs[tid] - sn*qs[tid+1]);
  int hh = tid >> 5, d = tid & 31;
  qrs[hh*33 + d] = qr;
  __syncthreads();
  const float* kvp = kv + (size_t)(b*NHH + hh)*HDD*HDD;
  float acc = 0.f;
  #pragma unroll
  for (int d2 = 0; d2 < HDD; ++d2) acc += qrs[hh*33 + d2] * kvp[d2*HDD + d];
  out[(size_t)row*CC0 + tid] = acc * zsh[hh];
}

// ---------------- LN over 768 of (a + f1), in-place into a (bf16); optional gelu ----------------
template<bool GELU>
__global__ __launch_bounds__(256) void lnadd768_kernel(bf16* __restrict__ a,
    const bf16* __restrict__ f1, const float* __restrict__ g, const float* __restrict__ bb){
  int row = blockIdx.x; int tid = threadIdx.x;
  size_t base = (size_t)row*C4;
  float v0 = b2f(a[base+tid])     + b2f(f1[base+tid]);
  float v1 = b2f(a[base+tid+256]) + b2f(f1[base+tid+256]);
  float v2 = b2f(a[base+tid+512]) + b2f(f1[base+tid+512]);
  float s = v0+v1+v2, q = v0*v0+v1*v1+v2*v2;
  #pragma unroll
  for (int m = 1; m < 64; m <<= 1){ s += __shfl_xor(s, m, 64); q += __shfl_xor(q, m, 64); }
  __shared__ float rs[4], rq[4];
  int wave = tid >> 6;
  if ((tid & 63) == 0){ rs[wave] = s; rq[wave] = q; }
  __syncthreads();
  float S = rs[0]+rs[1]+rs[2]+rs[3];
  float Q = rq[0]+rq[1]+rq[2]+rq[3];
  float mean = S * (1.f/C4);
  float rstd = rsqrtf(Q * (1.f/C4) - mean*mean + 1e-5f);
  #pragma unroll
  for (int p = 0; p < 3; ++p){
    int c = tid + p*256;
    float vv = (p==0? v0 : p==1? v1 : v2);
    float o = (vv-mean)*rstd*g[c] + bb[c];
    if constexpr (GELU) o = 0.5f*o*(1.f + erff(o*0.70710678118f));
    a[base+c] = f2b(o);
  }
}

extern "C" void kernel_launch(void* const* d_in, const int* in_sizes, int n_in,
                              void* d_out, int out_size, void* d_ws, size_t ws_size,
                              hipStream_t stream){
  (void)in_sizes; (void)n_in; (void)out_size; (void)ws_size;
  const float* X      = (const float*)d_in[0];
  const float* cpe1_w = (const float*)d_in[1];
  const float* cpe1_b = (const float*)d_in[2];
  const float* n1g    = (const float*)d_in[3];
  const float* n1b    = (const float*)d_in[4];
  const float* in_w   = (const float*)d_in[5];
  const float* in_b   = (const float*)d_in[6];
  const float* actp_w = (const float*)d_in[7];
  const float* actp_b = (const float*)d_in[8];
  const float* dwc_w  = (const float*)d_in[9];
  const float* dwc_b  = (const float*)d_in[10];
  const float* qk_w   = (const float*)d_in[11];
  const float* qk_b   = (const float*)d_in[12];
  const float* lepe_w = (const float*)d_in[13];
  const float* lepe_b = (const float*)d_in[14];
  const float* outp_w = (const float*)d_in[15];
  const float* outp_b = (const float*)d_in[16];
  const float* cpe2_w = (const float*)d_in[17];
  const float* cpe2_b = (const float*)d_in[18];
  const float* n2g    = (const float*)d_in[19];
  const float* n2b    = (const float*)d_in[20];
  const float* fc1_w  = (const float*)d_in[21];
  const float* fc1_b  = (const float*)d_in[22];
  const float* mdw_w  = (const float*)d_in[23];
  const float* mdw_b  = (const float*)d_in[24];
  const float* fc2_w  = (const float*)d_in[25];
  const float* fc2_b  = (const float*)d_in[26];
  const float* mn1g   = (const float*)d_in[27];
  const float* mn1b   = (const float*)d_in[28];
  const float* mn2g   = (const float*)d_in[29];
  const float* mn2b   = (const float*)d_in[30];
  const float* mn3g   = (const float*)d_in[31];
  const float* mn3b   = (const float*)d_in[32];

  char* ws = (char*)d_ws;
  const size_t SZF = (size_t)MROWS*CC0*4;   // 38,535,168
  const size_t SZB = (size_t)MROWS*CC0*2;   // 19,267,584
  float* A0 = (float*)(ws);                 // x1 -> x3
  float* A1 = (float*)(ws + 1*SZF);         // q -> x2
  float* A2 = (float*)(ws + 2*SZF);         // k -> attn(+lepe)
  bf16*  B0 = (bf16*)(ws + 3*SZF);          // xn -> xm
  bf16*  B1 = (bf16*)(ws + 3*SZF + 1*SZB);  // act_res
  bf16*  B2 = (bf16*)(ws + 3*SZF + 2*SZB);  // t
  bf16*  B3 = (bf16*)(ws + 3*SZF + 3*SZB);  // h
  bf16*  F1 = (bf16*)(ws + 1*SZF);          // f1 (77 MB, spans A1+A2; both dead)
  bf16*  DW = (bf16*)(ws + 3*SZF);          // dw chain (77 MB, spans B0..B3; dead)
  char* tail = ws + 3*SZF + 4*SZB;
  float* KMEAN = (float*)tail;                 tail += (size_t)BB*CC0*4;
  float* KV    = (float*)tail;                 tail += (size_t)BB*NHH*HDD*HDD*4;
  float* COS   = (float*)tail;                 tail += (size_t)NPOS*96*4;
  float* SIN   = (float*)tail;

  // 1. x1 = x + cpe1(x)
  dwconv_kernel<float,float,CC0,0><<<MROWS, CC0, 0, stream>>>(X, cpe1_w, cpe1_b, A0);
  rope_tables_kernel<<<(NPOS*96 + 255)/256, 256, 0, stream>>>(COS, SIN);
  // 2. xn = LN(x1) (bf16)
  ln192_kernel<<<MROWS, 64, 0, stream>>>(A0, n1g, n1b, B0);
  // 3. act_res = silu(xn@actp) (bf16)
  mfma_gemm<CC0,CC0,0,1><<<dim3(MROWS/BM,CC0/BN), 256, 0, stream>>>(B0, nullptr, actp_w, actp_b, nullptr, B1, nullptr);
  // 4. t = xn@in_w + b (bf16)
  mfma_gemm<CC0,CC0,0,0><<<dim3(MROWS/BM,CC0/BN), 256, 0, stream>>>(B0, nullptr, in_w, in_b, nullptr, B2, nullptr);
  // 5. h = silu(dwc(t)) (bf16)
  dwconv_kernel<bf16,bf16,CC0,1><<<MROWS, CC0, 0, stream>>>(B2, dwc_w, dwc_b, B3);
  // 6. qk = h@qk_w; q->A1, k->A2 (f32, elu+1)
  mfma_gemm<CC0,2*CC0,0,2><<<dim3(MROWS/BM,2*CC0/BN), 256, 0, stream>>>(B3, nullptr, qk_w, qk_b, nullptr, A1, A2);
  // 7. kmean, kv
  hipMemsetAsync(KMEAN, 0, (size_t)BB*CC0*4, stream);
  hipMemsetAsync(KV, 0, (size_t)BB*NHH*HDD*HDD*4, stream);
  kmean_kernel<<<BB*7, CC0, 0, stream>>>(A2, KMEAN);
  kv_kernel<<<BB*NHH*14, 256, 0, stream>>>(A2, B3, COS, SIN, KV);
  // 8. attn core -> A2 (k dead)
  attn_kernel<<<MROWS, CC0, 0, stream>>>(A1, KMEAN, KV, COS, SIN, A2);
  // 9. attn += lepe(h)
  dwconv_kernel<bf16,float,CC0,2><<<MROWS, CC0, 0, stream>>>(B3, lepe_w, lepe_b, A2);
  // 10. x2 = x1 + (attn*act_res)@outp + b -> A1 (q dead)
  mfma_gemm<CC0,CC0,1,3><<<dim3(MROWS/BM,CC0/BN), 256, 0, stream>>>(A2, B1, outp_w, outp_b, A0, A1, nullptr);
  // 11. x3 = x2 + cpe2(x2) -> A0
  dwconv_kernel<float,float,CC0,0><<<MROWS, CC0, 0, stream>>>(A1, cpe2_w, cpe2_b, A0);
  // 12. xm = LN(x3) (bf16) -> B0
  ln192_kernel<<<MROWS, 64, 0, stream>>>(A0, n2g, n2b, B0);
  // 13. f1 = xm@fc1 + b (bf16) -> F1 (A1+A2 dead)
  mfma_gemm<CC0,C4,0,0><<<dim3(MROWS/BM,C4/BN), 256, 0, stream>>>(B0, nullptr, fc1_w, fc1_b, nullptr, F1, nullptr);
  // 14. dw = mdw(f1) (bf16) -> DW (B0..B3 dead)
  dwconv_kernel<bf16,bf16,C4,3><<<MROWS, C4, 0, stream>>>(F1, mdw_w, mdw_b, DW);
  // 15. n1/n2/n3 chained LNs in-place; 3rd fuses gelu
  lnadd768_kernel<false><<<MROWS, 256, 0, stream>>>(DW, F1, mn1g, mn1b);
  lnadd768_kernel<false><<<MROWS, 256, 0, stream>>>(DW, F1, mn2g, mn2b);
  lnadd768_kernel<true><<<MROWS, 256, 0, stream>>>(DW, F1, mn3g, mn3b);
  // 16. out = x3 + gelu(n3)@fc2 + b (f32)
  mfma_gemm<C4,CC0,0,3><<<dim3(MROWS/BM,CC0/BN), 256, 0, stream>>>(DW, nullptr, fc2_w, fc2_b, A0, d_out, nullptr);
}

// Round 4
// 837.965 us; speedup vs baseline: 2.7549x; 1.4657x over previous
//
#include <hip/hip_runtime.h>
#include <hip/hip_bf16.h>
#include <math.h>

#define BB 16
#define HH 56
#define WW 56
#define CC0 192
#define NHH 6
#define HDD 32
#define NPOS (HH*WW)       // 3136
#define MROWS (BB*NPOS)    // 50176
#define C4 (4*CC0)         // 768

typedef __hip_bfloat16 bf16;
typedef short short8 __attribute__((ext_vector_type(8)));
typedef short short4v __attribute__((ext_vector_type(4)));
typedef float f32x4 __attribute__((ext_vector_type(4)));

__device__ __forceinline__ float b2f(bf16 v){ return __bfloat162float(v); }
__device__ __forceinline__ bf16 f2b(float v){ return __float2bfloat16(v); }
__device__ __forceinline__ short f2s(float v){ bf16 b = __float2bfloat16(v); return *(short*)&b; }
__device__ __forceinline__ float s2f(short s){ bf16 b; *(short*)&b = s; return __bfloat162float(b); }

// ---------------- vectorized depthwise 3x3 conv ----------------
// One 16B channel-group per thread. VEC = 8 (bf16) or 4 (f32).
// MODE 0: out(f32) = in(f32) + conv+bias     (cpe1/cpe2)
// MODE 1: out(bf16) = silu(conv+bias)        (dwc, in bf16)
// MODE 2: out(f32) += conv+bias              (lepe, in bf16)
// MODE 3: out(bf16) = conv+bias              (mdw, in bf16)
template<typename TIN, int CC, int MODE>
__global__ __launch_bounds__(256) void dwconv_v(const TIN* __restrict__ in,
    const float* __restrict__ w, const float* __restrict__ bias, void* __restrict__ out){
  constexpr int VEC = 16 / (int)sizeof(TIN);
  constexpr int NG = CC / VEC;
  int idx = blockIdx.x*256 + threadIdx.x;
  int cg = idx % NG; int pos = idx / NG;
  int b = pos / NPOS; int ij = pos % NPOS; int i = ij / WW; int j = ij % WW;
  int cb = cg * VEC;
  float acc[VEC];
  #pragma unroll
  for (int l = 0; l < VEC; ++l) acc[l] = bias[cb + l];
  #pragma unroll
  for (int di = 0; di < 3; ++di){
    int ii = i + di - 1;
    if (ii < 0 || ii >= HH) continue;
    #pragma unroll
    for (int dj = 0; dj < 3; ++dj){
      int jj = j + dj - 1;
      if (jj < 0 || jj >= WW) continue;
      size_t off = ((size_t)b*NPOS + ii*WW + jj)*CC + cb;
      const float* wp = w + (di*3 + dj)*CC + cb;
      if constexpr (sizeof(TIN) == 2){
        short8 v = *(const short8*)((const short*)in + off);
        #pragma unroll
        for (int l = 0; l < 8; ++l) acc[l] += s2f(v[l]) * wp[l];
      } else {
        f32x4 v = *(const f32x4*)((const float*)in + off);
        #pragma unroll
        for (int l = 0; l < 4; ++l) acc[l] += v[l] * wp[l];
      }
    }
  }
  size_t oidx = (size_t)pos*CC + cb;
  if constexpr (MODE == 0){
    f32x4 r = *(const f32x4*)((const float*)in + oidx);
    f32x4 o;
    #pragma unroll
    for (int l = 0; l < 4; ++l) o[l] = r[l] + acc[l];
    *(f32x4*)((float*)out + oidx) = o;
  } else if constexpr (MODE == 1){
    short8 o;
    #pragma unroll
    for (int l = 0; l < 8; ++l){ float s = acc[l]/(1.f + expf(-acc[l])); o[l] = f2s(s); }
    *(short8*)((short*)out + oidx) = o;
  } else if constexpr (MODE == 2){
    float* op = (float*)out + oidx;
    f32x4 r0 = *(f32x4*)op, r1 = *(f32x4*)(op + 4);
    #pragma unroll
    for (int l = 0; l < 4; ++l){ r0[l] += acc[l]; r1[l] += acc[l+4]; }
    *(f32x4*)op = r0; *(f32x4*)(op + 4) = r1;
  } else {
    short8 o;
    #pragma unroll
    for (int l = 0; l < 8; ++l) o[l] = f2s(acc[l]);
    *(short8*)((short*)out + oidx) = o;
  }
}

// ---------------- LayerNorm over C=192 (f32 in, bf16 out) ----------------
__global__ __launch_bounds__(64) void ln192_kernel(const float* __restrict__ x,
    const float* __restrict__ g, const float* __restrict__ bb, bf16* __restrict__ out){
  int row = blockIdx.x; int t = threadIdx.x;
  const float* xr = x + (size_t)row*CC0;
  float v0 = xr[t], v1 = xr[t+64], v2 = xr[t+128];
  float s = v0+v1+v2;
  float q = v0*v0+v1*v1+v2*v2;
  #pragma unroll
  for (int m = 1; m < 64; m <<= 1){ s += __shfl_xor(s, m, 64); q += __shfl_xor(q, m, 64); }
  float mean = s * (1.f/CC0);
  float rstd = rsqrtf(q * (1.f/CC0) - mean*mean + 1e-5f);
  bf16* orow = out + (size_t)row*CC0;
  orow[t]     = f2b((v0-mean)*rstd*g[t]     + bb[t]);
  orow[t+64]  = f2b((v1-mean)*rstd*g[t+64]  + bb[t+64]);
  orow[t+128] = f2b((v2-mean)*rstd*g[t+128] + bb[t+128]);
}

// ---------------- MFMA GEMM: [MROWS,K](bf16-ish) @ [K,N](f32 w) + bias ----------------
// ALOAD: 0 = bf16 direct, 1 = f32 * bf16 product (attn * act_res)
// EPI:   0 = store bf16, 1 = silu->bf16, 2 = elu+1 split q/k ->f32,
//        3 = +addf(f32) -> f32
#define BM 256
#define BN 64
#define BK 32
#define LDA 40
template<int K, int N, int ALOAD, int EPI>
__global__ __launch_bounds__(256) void mfma_gemm(
    const void* __restrict__ a0v, const bf16* __restrict__ a1v,
    const float* __restrict__ w, const float* __restrict__ bias,
    const float* __restrict__ addf, void* __restrict__ out0, void* __restrict__ out1){
  __shared__ short As[BM*LDA];
  __shared__ short Bs[BN*LDA];
  int tid = threadIdx.x;
  int wave = tid >> 6, lane = tid & 63;
  size_t m0 = (size_t)blockIdx.x * BM;
  int n0 = blockIdx.y * BN;
  int wm = wave * 64;
  int am = lane & 15, ak = (lane >> 4) * 8;

  f32x4 acc[4][4];
  #pragma unroll
  for (int mt = 0; mt < 4; ++mt)
    #pragma unroll
    for (int nt = 0; nt < 4; ++nt)
      acc[mt][nt] = (f32x4){0.f,0.f,0.f,0.f};

  for (int k0 = 0; k0 < K; k0 += BK){
    if constexpr (ALOAD == 0){
      const short* A = (const short*)a0v;
      #pragma unroll
      for (int it = 0; it < 4; ++it){
        int idx = it*256 + tid;
        int row = idx >> 2; int ko = (idx & 3) * 8;
        short8 v = *(const short8*)(A + (m0 + row)*(size_t)K + k0 + ko);
        *(short8*)&As[row*LDA + ko] = v;
      }
    } else {
      const float* A = (const float*)a0v;
      #pragma unroll
      for (int it = 0; it < 8; ++it){
        int idx = it*256 + tid;
        int row = idx >> 3; int kq = (idx & 7) * 4;
        size_t off = (m0 + row)*(size_t)K + k0 + kq;
        f32x4 v = *(const f32x4*)(A + off);
        short4v sv = *(const short4v*)((const short*)a1v + off);
        short4v o;
        o.x = f2s(v.x * s2f(sv.x)); o.y = f2s(v.y * s2f(sv.y));
        o.z = f2s(v.z * s2f(sv.z)); o.w = f2s(v.w * s2f(sv.w));
        *(short4v*)&As[row*LDA + kq] = o;
      }
    }
    #pragma unroll
    for (int it = 0; it < 8; ++it){
      int idx = it*256 + tid;
      int kk = idx >> 6, nn = idx & 63;
      float wv = w[(size_t)(k0 + kk)*N + n0 + nn];
      Bs[nn*LDA + kk] = f2s(wv);
    }
    __syncthreads();
    short8 af[4], bfr[4];
    #pragma unroll
    for (int mt = 0; mt < 4; ++mt) af[mt] = *(short8*)&As[(wm + mt*16 + am)*LDA + ak];
    #pragma unroll
    for (int nt = 0; nt < 4; ++nt) bfr[nt] = *(short8*)&Bs[(nt*16 + am)*LDA + ak];
    #pragma unroll
    for (int mt = 0; mt < 4; ++mt)
      #pragma unroll
      for (int nt = 0; nt < 4; ++nt)
        acc[mt][nt] = __builtin_amdgcn_mfma_f32_16x16x32_bf16(af[mt], bfr[nt], acc[mt][nt], 0, 0, 0);
    __syncthreads();
  }

  int cn = lane & 15;
  int cr = (lane >> 4) * 4;
  #pragma unroll
  for (int mt = 0; mt < 4; ++mt){
    #pragma unroll
    for (int nt = 0; nt < 4; ++nt){
      int gn = n0 + nt*16 + cn;
      float bv = bias[gn];
      #pragma unroll
      for (int r = 0; r < 4; ++r){
        size_t gm = m0 + wm + mt*16 + cr + r;
        float v = acc[mt][nt][r] + bv;
        if constexpr (EPI == 0){
          ((bf16*)out0)[gm*N + gn] = f2b(v);
        } else if constexpr (EPI == 1){
          ((bf16*)out0)[gm*N + gn] = f2b(v / (1.f + expf(-v)));
        } else if constexpr (EPI == 2){
          float rv = (v > 0.f) ? (v + 1.f) : expf(v);
          if (n0 < CC0) ((float*)out0)[gm*CC0 + gn] = rv;
          else          ((float*)out1)[gm*CC0 + (gn - CC0)] = rv;
        } else {
          ((float*)out0)[gm*N + gn] = addf[gm*N + gn] + v;
        }
      }
    }
  }
}

// ---------------- RoPE tables (H,W,96) ----------------
__global__ void rope_tables_kernel(float* __restrict__ cosT, float* __restrict__ sinT){
  int idx = blockIdx.x*256 + threadIdx.x;
  if (idx >= NPOS*96) return;
  int t = idx % 96; int ij = idx / 96; int i = ij / WW; int j = ij % WW;
  int kk = (t < 48) ? t : (t - 48);
  float th = expf(-(float)kk * 0.19188209108283716f);  // 10000^(-k/48)
  float pos = (t < 48) ? (float)i : (float)j;
  float ang = pos * th;
  cosT[idx] = cosf(ang);
  sinT[idx] = sinf(ang);
}

// ---------------- kmean: mean over N of k ----------------
__global__ __launch_bounds__(CC0) void kmean_kernel(const float* __restrict__ k, float* __restrict__ kmean){
  int b = blockIdx.x / 7; int chunk = blockIdx.x % 7; int c = threadIdx.x;
  const float* kp = k + ((size_t)b*NPOS + (size_t)chunk*448)*CC0 + c;
  float s = 0.f;
  for (int r = 0; r < 448; ++r) s += kp[(size_t)r*CC0];
  atomicAdd(&kmean[b*CC0 + c], s * (1.f/NPOS));
}

// ---------------- kv = sum_n rope(k)[d] * v[e] / N ----------------
__global__ __launch_bounds__(256) void kv_kernel(const float* __restrict__ kbuf,
    const bf16* __restrict__ hbuf, const float* __restrict__ cosT,
    const float* __restrict__ sinT, float* __restrict__ kv){
  int bi = blockIdx.x;
  int chunk = bi % 14; bi /= 14;
  int h = bi % NHH; int b = bi / NHH;
  int tid = threadIdx.x;
  int r8 = tid >> 5, lane = tid & 31;
  __shared__ float krs[8][32];
  __shared__ float vvs[8][32];
  int d = tid >> 3; int ebase = (tid & 7) * 4;
  float a0 = 0.f, a1 = 0.f, a2 = 0.f, a3 = 0.f;
  int c = h*HDD + lane;
  int t = c >> 1;
  bool odd = (lane & 1);
  for (int step = 0; step < 28; ++step){
    int n = chunk*224 + step*8 + r8;
    size_t row = (size_t)b*NPOS + n;
    float kc = kbuf[row*CC0 + c];
    float kp = kbuf[row*CC0 + (c ^ 1)];
    float cs = cosT[(size_t)n*96 + t], sn = sinT[(size_t)n*96 + t];
    krs[r8][lane] = odd ? (cs*kc + sn*kp) : (cs*kc - sn*kp);
    vvs[r8][lane] = b2f(hbuf[row*CC0 + c]);
    __syncthreads();
    #pragma unroll
    for (int nn = 0; nn < 8; ++nn){
      float kk2 = krs[nn][d];
      a0 += kk2 * vvs[nn][ebase+0];
      a1 += kk2 * vvs[nn][ebase+1];
      a2 += kk2 * vvs[nn][ebase+2];
      a3 += kk2 * vvs[nn][ebase+3];
    }
    __syncthreads();
  }
  const float invN = 1.f/NPOS;
  float* kvp = kv + (((size_t)(b*NHH + h)*HDD + d)*HDD) + ebase;
  atomicAdd(kvp+0, a0*invN);
  atomicAdd(kvp+1, a1*invN);
  atomicAdd(kvp+2, a2*invN);
  atomicAdd(kvp+3, a3*invN);
}

// ---------------- fused attention: z + rope(q) + q_r@kv ----------------
__global__ __launch_bounds__(CC0) void attn_kernel(const float* __restrict__ q,
    const float* __restrict__ kmean, const float* __restrict__ kv,
    const float* __restrict__ cosT, const float* __restrict__ sinT,
    float* __restrict__ out){
  int row = blockIdx.x;
  int tid = threadIdx.x;
  int b = row / NPOS; int n = row % NPOS;
  __shared__ float qs[CC0];
  __shared__ float qrs[NHH*33];
  __shared__ float zsh[NHH];
  qs[tid] = q[(size_t)row*CC0 + tid];
  __syncthreads();
  float pm = qs[tid] * kmean[b*CC0 + tid];
  #pragma unroll
  for (int m = 16; m >= 1; m >>= 1) pm += __shfl_xor(pm, m, 32);
  if ((tid & 31) == 0) zsh[tid >> 5] = 1.f/(pm + 1e-6f);
  int t = tid >> 1;
  float cs = cosT[(size_t)n*96 + t], sn = sinT[(size_t)n*96 + t];
  float qr = (tid & 1) ? (cs*qs[tid] + sn*qs[tid-1]) : (cs*qs[tid] - sn*qs[tid+1]);
  int hh = tid >> 5, d = tid & 31;
  qrs[hh*33 + d] = qr;
  __syncthreads();
  const float* kvp = kv + (size_t)(b*NHH + hh)*HDD*HDD;
  float acc = 0.f;
  #pragma unroll
  for (int d2 = 0; d2 < HDD; ++d2) acc += qrs[hh*33 + d2] * kvp[d2*HDD + d];
  out[(size_t)row*CC0 + tid] = acc * zsh[hh];
}

// ---------------- fused chain: n1=LN(dw+f1); n2=LN(n1+f1); n3=LN(n2+f1); out=gelu(n3) ----------------
__global__ __launch_bounds__(256) void ln_chain_kernel(bf16* __restrict__ a,
    const bf16* __restrict__ f1,
    const float* __restrict__ g1, const float* __restrict__ b1,
    const float* __restrict__ g2, const float* __restrict__ b2,
    const float* __restrict__ g3, const float* __restrict__ b3){
  int row = blockIdx.x; int tid = threadIdx.x;
  size_t base = (size_t)row*C4;
  __shared__ float rs[4], rq[4];
  int wave = tid >> 6;
  float f[3], v[3];
  #pragma unroll
  for (int p = 0; p < 3; ++p){
    f[p] = b2f(f1[base + tid + p*256]);
    v[p] = b2f(a[base + tid + p*256]) + f[p];
  }
  const float* gs[3] = {g1, g2, g3};
  const float* bs[3] = {b1, b2, b3};
  #pragma unroll
  for (int pass = 0; pass < 3; ++pass){
    float s = v[0]+v[1]+v[2], q = v[0]*v[0]+v[1]*v[1]+v[2]*v[2];
    #pragma unroll
    for (int m = 1; m < 64; m <<= 1){ s += __shfl_xor(s, m, 64); q += __shfl_xor(q, m, 64); }
    if ((tid & 63) == 0){ rs[wave] = s; rq[wave] = q; }
    __syncthreads();
    float S = rs[0]+rs[1]+rs[2]+rs[3];
    float Q = rq[0]+rq[1]+rq[2]+rq[3];
    __syncthreads();
    float mean = S * (1.f/C4);
    float rstd = rsqrtf(Q * (1.f/C4) - mean*mean + 1e-5f);
    #pragma unroll
    for (int p = 0; p < 3; ++p){
      int c = tid + p*256;
      v[p] = (v[p]-mean)*rstd*gs[pass][c] + bs[pass][c];
      if (pass < 2) v[p] += f[p];
    }
  }
  #pragma unroll
  for (int p = 0; p < 3; ++p){
    float o = v[p];
    o = 0.5f*o*(1.f + erff(o*0.70710678118f));
    a[base + tid + p*256] = f2b(o);
  }
}

extern "C" void kernel_launch(void* const* d_in, const int* in_sizes, int n_in,
                              void* d_out, int out_size, void* d_ws, size_t ws_size,
                              hipStream_t stream){
  (void)in_sizes; (void)n_in; (void)out_size; (void)ws_size;
  const float* X      = (const float*)d_in[0];
  const float* cpe1_w = (const float*)d_in[1];
  const float* cpe1_b = (const float*)d_in[2];
  const float* n1g    = (const float*)d_in[3];
  const float* n1b    = (const float*)d_in[4];
  const float* in_w   = (const float*)d_in[5];
  const float* in_b   = (const float*)d_in[6];
  const float* actp_w = (const float*)d_in[7];
  const float* actp_b = (const float*)d_in[8];
  const float* dwc_w  = (const float*)d_in[9];
  const float* dwc_b  = (const float*)d_in[10];
  const float* qk_w   = (const float*)d_in[11];
  const float* qk_b   = (const float*)d_in[12];
  const float* lepe_w = (const float*)d_in[13];
  const float* lepe_b = (const float*)d_in[14];
  const float* outp_w = (const float*)d_in[15];
  const float* outp_b = (const float*)d_in[16];
  const float* cpe2_w = (const float*)d_in[17];
  const float* cpe2_b = (const float*)d_in[18];
  const float* n2g    = (const float*)d_in[19];
  const float* n2b    = (const float*)d_in[20];
  const float* fc1_w  = (const float*)d_in[21];
  const float* fc1_b  = (const float*)d_in[22];
  const float* fc2_w  = (const float*)d_in[25];
  const float* fc2_b  = (const float*)d_in[26];
  const float* mdw_w  = (const float*)d_in[23];
  const float* mdw_b  = (const float*)d_in[24];
  const float* mn1g   = (const float*)d_in[27];
  const float* mn1b   = (const float*)d_in[28];
  const float* mn2g   = (const float*)d_in[29];
  const float* mn2b   = (const float*)d_in[30];
  const float* mn3g   = (const float*)d_in[31];
  const float* mn3b   = (const float*)d_in[32];

  char* ws = (char*)d_ws;
  const size_t SZF = (size_t)MROWS*CC0*4;   // 38,535,168
  const size_t SZB = (size_t)MROWS*CC0*2;   // 19,267,584
  float* A0 = (float*)(ws);                 // x1 -> x3
  float* A1 = (float*)(ws + 1*SZF);         // q -> x2
  float* A2 = (float*)(ws + 2*SZF);         // k -> attn(+lepe)
  bf16*  B0 = (bf16*)(ws + 3*SZF);          // xn -> xm
  bf16*  B1 = (bf16*)(ws + 3*SZF + 1*SZB);  // act_res
  bf16*  B2 = (bf16*)(ws + 3*SZF + 2*SZB);  // t
  bf16*  B3 = (bf16*)(ws + 3*SZF + 3*SZB);  // h
  bf16*  F1 = (bf16*)(ws + 1*SZF);          // f1 (77 MB, spans A1+A2; both dead)
  bf16*  DW = (bf16*)(ws + 3*SZF);          // dw chain (77 MB, spans B0..B3; dead)
  char* tail = ws + 3*SZF + 4*SZB;
  float* KMEAN = (float*)tail;                 tail += (size_t)BB*CC0*4;
  float* KV    = (float*)tail;                 tail += (size_t)BB*NHH*HDD*HDD*4;
  float* COS   = (float*)tail;                 tail += (size_t)NPOS*96*4;
  float* SIN   = (float*)tail;

  const int G192F = (MROWS*(CC0/4))/256;   // f32 VEC=4  -> 9408 blocks
  const int G192B = (MROWS*(CC0/8))/256;   // bf16 VEC=8 -> 4704 blocks
  const int G768B = (MROWS*(C4/8))/256;    // bf16 VEC=8 -> 18816 blocks

  // 1. x1 = x + cpe1(x)
  dwconv_v<float,CC0,0><<<G192F, 256, 0, stream>>>(X, cpe1_w, cpe1_b, A0);
  rope_tables_kernel<<<(NPOS*96 + 255)/256, 256, 0, stream>>>(COS, SIN);
  // 2. xn = LN(x1) (bf16)
  ln192_kernel<<<MROWS, 64, 0, stream>>>(A0, n1g, n1b, B0);
  // 3. act_res = silu(xn@actp) (bf16)
  mfma_gemm<CC0,CC0,0,1><<<dim3(MROWS/BM,CC0/BN), 256, 0, stream>>>(B0, nullptr, actp_w, actp_b, nullptr, B1, nullptr);
  // 4. t = xn@in_w + b (bf16)
  mfma_gemm<CC0,CC0,0,0><<<dim3(MROWS/BM,CC0/BN), 256, 0, stream>>>(B0, nullptr, in_w, in_b, nullptr, B2, nullptr);
  // 5. h = silu(dwc(t)) (bf16)
  dwconv_v<bf16,CC0,1><<<G192B, 256, 0, stream>>>(B2, dwc_w, dwc_b, B3);
  // 6. qk = h@qk_w; q->A1, k->A2 (f32, elu+1)
  mfma_gemm<CC0,2*CC0,0,2><<<dim3(MROWS/BM,2*CC0/BN), 256, 0, stream>>>(B3, nullptr, qk_w, qk_b, nullptr, A1, A2);
  // 7. kmean, kv
  hipMemsetAsync(KMEAN, 0, (size_t)BB*CC0*4, stream);
  hipMemsetAsync(KV, 0, (size_t)BB*NHH*HDD*HDD*4, stream);
  kmean_kernel<<<BB*7, CC0, 0, stream>>>(A2, KMEAN);
  kv_kernel<<<BB*NHH*14, 256, 0, stream>>>(A2, B3, COS, SIN, KV);
  // 8. attn core -> A2 (k dead)
  attn_kernel<<<MROWS, CC0, 0, stream>>>(A1, KMEAN, KV, COS, SIN, A2);
  // 9. attn += lepe(h)
  dwconv_v<bf16,CC0,2><<<G192B, 256, 0, stream>>>(B3, lepe_w, lepe_b, A2);
  // 10. x2 = x1 + (attn*act_res)@outp + b -> A1 (q dead)
  mfma_gemm<CC0,CC0,1,3><<<dim3(MROWS/BM,CC0/BN), 256, 0, stream>>>(A2, B1, outp_w, outp_b, A0, A1, nullptr);
  // 11. x3 = x2 + cpe2(x2) -> A0
  dwconv_v<float,CC0,0><<<G192F, 256, 0, stream>>>(A1, cpe2_w, cpe2_b, A0);
  // 12. xm = LN(x3) (bf16) -> B0
  ln192_kernel<<<MROWS, 64, 0, stream>>>(A0, n2g, n2b, B0);
  // 13. f1 = xm@fc1 + b (bf16) -> F1 (A1+A2 dead)
  mfma_gemm<CC0,C4,0,0><<<dim3(MROWS/BM,C4/BN), 256, 0, stream>>>(B0, nullptr, fc1_w, fc1_b, nullptr, F1, nullptr);
  // 14. dw = mdw(f1) (bf16) -> DW (B0..B3 dead)
  dwconv_v<bf16,C4,3><<<G768B, 256, 0, stream>>>(F1, mdw_w, mdw_b, DW);
  // 15. fused n1/n2/n3 + gelu, in-place in DW
  ln_chain_kernel<<<MROWS, 256, 0, stream>>>(DW, F1, mn1g, mn1b, mn2g, mn2b, mn3g, mn3b);
  // 16. out = x3 + gelu(n3)@fc2 + b (f32)
  mfma_gemm<C4,CC0,0,3><<<dim3(MROWS/BM,CC0/BN), 256, 0, stream>>>(DW, nullptr, fc2_w, fc2_b, A0, d_out, nullptr);
}

// Round 5
// 836.723 us; speedup vs baseline: 2.7589x; 1.0015x over previous
//
#include <hip/hip_runtime.h>
#include <hip/hip_bf16.h>
#include <math.h>

#define BB 16
#define HH 56
#define WW 56
#define CC0 192
#define NHH 6
#define HDD 32
#define NPOS (HH*WW)       // 3136
#define MROWS (BB*NPOS)    // 50176
#define C4 (4*CC0)         // 768

typedef __hip_bfloat16 bf16;
typedef short short8 __attribute__((ext_vector_type(8)));
typedef short short4v __attribute__((ext_vector_type(4)));
typedef float f32x4 __attribute__((ext_vector_type(4)));

__device__ __forceinline__ float b2f(bf16 v){ return __bfloat162float(v); }
__device__ __forceinline__ bf16 f2b(float v){ return __float2bfloat16(v); }
__device__ __forceinline__ short f2s(float v){ bf16 b = __float2bfloat16(v); return *(short*)&b; }
__device__ __forceinline__ float s2f(short s){ bf16 b; *(short*)&b = s; return __bfloat162float(b); }
__device__ __forceinline__ float fast_gelu(float x){
  float u = 1.5957691216f * (x + 0.044715f*x*x*x);   // 2*0.79788456*(x+...)
  float t = 1.f - 2.f/(__expf(u) + 1.f);             // tanh(u/2*2)=tanh form
  return 0.5f*x*(1.f + t);
}

// ---------------- vectorized depthwise 3x3 conv ----------------
// MODE 0: out(f32) = in(f32) + conv+bias     (cpe1/cpe2)
// MODE 1: out(bf16) = silu(conv+bias)        (dwc, in bf16)
// MODE 2: out(f32) += conv+bias              (lepe, in bf16)
template<typename TIN, int CC, int MODE>
__global__ __launch_bounds__(256) void dwconv_v(const TIN* __restrict__ in,
    const float* __restrict__ w, const float* __restrict__ bias, void* __restrict__ out){
  constexpr int VEC = 16 / (int)sizeof(TIN);
  constexpr int NG = CC / VEC;
  int idx = blockIdx.x*256 + threadIdx.x;
  int cg = idx % NG; int pos = idx / NG;
  int b = pos / NPOS; int ij = pos % NPOS; int i = ij / WW; int j = ij % WW;
  int cb = cg * VEC;
  float acc[VEC];
  #pragma unroll
  for (int l = 0; l < VEC; ++l) acc[l] = bias[cb + l];
  #pragma unroll
  for (int di = 0; di < 3; ++di){
    int ii = i + di - 1;
    if (ii < 0 || ii >= HH) continue;
    #pragma unroll
    for (int dj = 0; dj < 3; ++dj){
      int jj = j + dj - 1;
      if (jj < 0 || jj >= WW) continue;
      size_t off = ((size_t)b*NPOS + ii*WW + jj)*CC + cb;
      const float* wp = w + (di*3 + dj)*CC + cb;
      if constexpr (sizeof(TIN) == 2){
        short8 v = *(const short8*)((const short*)in + off);
        #pragma unroll
        for (int l = 0; l < 8; ++l) acc[l] += s2f(v[l]) * wp[l];
      } else {
        f32x4 v = *(const f32x4*)((const float*)in + off);
        #pragma unroll
        for (int l = 0; l < 4; ++l) acc[l] += v[l] * wp[l];
      }
    }
  }
  size_t oidx = (size_t)pos*CC + cb;
  if constexpr (MODE == 0){
    f32x4 r = *(const f32x4*)((const float*)in + oidx);
    f32x4 o;
    #pragma unroll
    for (int l = 0; l < 4; ++l) o[l] = r[l] + acc[l];
    *(f32x4*)((float*)out + oidx) = o;
  } else if constexpr (MODE == 1){
    short8 o;
    #pragma unroll
    for (int l = 0; l < 8; ++l){ float s = acc[l]/(1.f + expf(-acc[l])); o[l] = f2s(s); }
    *(short8*)((short*)out + oidx) = o;
  } else {
    float* op = (float*)out + oidx;
    f32x4 r0 = *(f32x4*)op, r1 = *(f32x4*)(op + 4);
    #pragma unroll
    for (int l = 0; l < 4; ++l){ r0[l] += acc[l]; r1[l] += acc[l+4]; }
    *(f32x4*)op = r0; *(f32x4*)(op + 4) = r1;
  }
}

// ---------------- LayerNorm over C=192 (f32 in, bf16 out) ----------------
__global__ __launch_bounds__(64) void ln192_kernel(const float* __restrict__ x,
    const float* __restrict__ g, const float* __restrict__ bb, bf16* __restrict__ out){
  int row = blockIdx.x; int t = threadIdx.x;
  const float* xr = x + (size_t)row*CC0;
  float v0 = xr[t], v1 = xr[t+64], v2 = xr[t+128];
  float s = v0+v1+v2;
  float q = v0*v0+v1*v1+v2*v2;
  #pragma unroll
  for (int m = 1; m < 64; m <<= 1){ s += __shfl_xor(s, m, 64); q += __shfl_xor(q, m, 64); }
  float mean = s * (1.f/CC0);
  float rstd = rsqrtf(q * (1.f/CC0) - mean*mean + 1e-5f);
  bf16* orow = out + (size_t)row*CC0;
  orow[t]     = f2b((v0-mean)*rstd*g[t]     + bb[t]);
  orow[t+64]  = f2b((v1-mean)*rstd*g[t+64]  + bb[t+64]);
  orow[t+128] = f2b((v2-mean)*rstd*g[t+128] + bb[t+128]);
}

// ---------------- MFMA GEMM ----------------
// ALOAD: 0 = bf16 direct, 1 = f32 * bf16 product
// EPI: 0 = bf16, 1 = silu->bf16, 2 = elu+1 split ->f32, 3 = +addf ->f32
#define BM 256
#define BN 64
#define BK 32
#define LDA 40
template<int K, int N, int ALOAD, int EPI>
__global__ __launch_bounds__(256) void mfma_gemm(
    const void* __restrict__ a0v, const bf16* __restrict__ a1v,
    const float* __restrict__ w, const float* __restrict__ bias,
    const float* __restrict__ addf, void* __restrict__ out0, void* __restrict__ out1){
  __shared__ short As[BM*LDA];
  __shared__ short Bs[BN*LDA];
  int tid = threadIdx.x;
  int wave = tid >> 6, lane = tid & 63;
  size_t m0 = (size_t)blockIdx.x * BM;
  int n0 = blockIdx.y * BN;
  int wm = wave * 64;
  int am = lane & 15, ak = (lane >> 4) * 8;

  f32x4 acc[4][4];
  #pragma unroll
  for (int mt = 0; mt < 4; ++mt)
    #pragma unroll
    for (int nt = 0; nt < 4; ++nt)
      acc[mt][nt] = (f32x4){0.f,0.f,0.f,0.f};

  for (int k0 = 0; k0 < K; k0 += BK){
    if constexpr (ALOAD == 0){
      const short* A = (const short*)a0v;
      #pragma unroll
      for (int it = 0; it < 4; ++it){
        int idx = it*256 + tid;
        int row = idx >> 2; int ko = (idx & 3) * 8;
        short8 v = *(const short8*)(A + (m0 + row)*(size_t)K + k0 + ko);
        *(short8*)&As[row*LDA + ko] = v;
      }
    } else {
      const float* A = (const float*)a0v;
      #pragma unroll
      for (int it = 0; it < 8; ++it){
        int idx = it*256 + tid;
        int row = idx >> 3; int kq = (idx & 7) * 4;
        size_t off = (m0 + row)*(size_t)K + k0 + kq;
        f32x4 v = *(const f32x4*)(A + off);
        short4v sv = *(const short4v*)((const short*)a1v + off);
        short4v o;
        o.x = f2s(v.x * s2f(sv.x)); o.y = f2s(v.y * s2f(sv.y));
        o.z = f2s(v.z * s2f(sv.z)); o.w = f2s(v.w * s2f(sv.w));
        *(short4v*)&As[row*LDA + kq] = o;
      }
    }
    #pragma unroll
    for (int it = 0; it < 8; ++it){
      int idx = it*256 + tid;
      int kk = idx >> 6, nn = idx & 63;
      float wv = w[(size_t)(k0 + kk)*N + n0 + nn];
      Bs[nn*LDA + kk] = f2s(wv);
    }
    __syncthreads();
    short8 af[4], bfr[4];
    #pragma unroll
    for (int mt = 0; mt < 4; ++mt) af[mt] = *(short8*)&As[(wm + mt*16 + am)*LDA + ak];
    #pragma unroll
    for (int nt = 0; nt < 4; ++nt) bfr[nt] = *(short8*)&Bs[(nt*16 + am)*LDA + ak];
    #pragma unroll
    for (int mt = 0; mt < 4; ++mt)
      #pragma unroll
      for (int nt = 0; nt < 4; ++nt)
        acc[mt][nt] = __builtin_amdgcn_mfma_f32_16x16x32_bf16(af[mt], bfr[nt], acc[mt][nt], 0, 0, 0);
    __syncthreads();
  }

  int cn = lane & 15;
  int cr = (lane >> 4) * 4;
  #pragma unroll
  for (int mt = 0; mt < 4; ++mt){
    #pragma unroll
    for (int nt = 0; nt < 4; ++nt){
      int gn = n0 + nt*16 + cn;
      float bv = bias[gn];
      #pragma unroll
      for (int r = 0; r < 4; ++r){
        size_t gm = m0 + wm + mt*16 + cr + r;
        float v = acc[mt][nt][r] + bv;
        if constexpr (EPI == 0){
          ((bf16*)out0)[gm*N + gn] = f2b(v);
        } else if constexpr (EPI == 1){
          ((bf16*)out0)[gm*N + gn] = f2b(v / (1.f + expf(-v)));
        } else if constexpr (EPI == 2){
          float rv = (v > 0.f) ? (v + 1.f) : expf(v);
          if (n0 < CC0) ((float*)out0)[gm*CC0 + gn] = rv;
          else          ((float*)out1)[gm*CC0 + (gn - CC0)] = rv;
        } else {
          ((float*)out0)[gm*N + gn] = addf[gm*N + gn] + v;
        }
      }
    }
  }
}

// ---------------- RoPE tables (H,W,96) ----------------
__global__ void rope_tables_kernel(float* __restrict__ cosT, float* __restrict__ sinT){
  int idx = blockIdx.x*256 + threadIdx.x;
  if (idx >= NPOS*96) return;
  int t = idx % 96; int ij = idx / 96; int i = ij / WW; int j = ij % WW;
  int kk = (t < 48) ? t : (t - 48);
  float th = expf(-(float)kk * 0.19188209108283716f);
  float pos = (t < 48) ? (float)i : (float)j;
  float ang = pos * th;
  cosT[idx] = cosf(ang);
  sinT[idx] = sinf(ang);
}

// ---------------- kmean ----------------
__global__ __launch_bounds__(CC0) void kmean_kernel(const float* __restrict__ k, float* __restrict__ kmean){
  int b = blockIdx.x / 7; int chunk = blockIdx.x % 7; int c = threadIdx.x;
  const float* kp = k + ((size_t)b*NPOS + (size_t)chunk*448)*CC0 + c;
  float s = 0.f;
  for (int r = 0; r < 448; ++r) s += kp[(size_t)r*CC0];
  atomicAdd(&kmean[b*CC0 + c], s * (1.f/NPOS));
}

// ---------------- kv ----------------
__global__ __launch_bounds__(256) void kv_kernel(const float* __restrict__ kbuf,
    const bf16* __restrict__ hbuf, const float* __restrict__ cosT,
    const float* __restrict__ sinT, float* __restrict__ kv){
  int bi = blockIdx.x;
  int chunk = bi % 14; bi /= 14;
  int h = bi % NHH; int b = bi / NHH;
  int tid = threadIdx.x;
  int r8 = tid >> 5, lane = tid & 31;
  __shared__ float krs[8][32];
  __shared__ float vvs[8][32];
  int d = tid >> 3; int ebase = (tid & 7) * 4;
  float a0 = 0.f, a1 = 0.f, a2 = 0.f, a3 = 0.f;
  int c = h*HDD + lane;
  int t = c >> 1;
  bool odd = (lane & 1);
  for (int step = 0; step < 28; ++step){
    int n = chunk*224 + step*8 + r8;
    size_t row = (size_t)b*NPOS + n;
    float kc = kbuf[row*CC0 + c];
    float kp = kbuf[row*CC0 + (c ^ 1)];
    float cs = cosT[(size_t)n*96 + t], sn = sinT[(size_t)n*96 + t];
    krs[r8][lane] = odd ? (cs*kc + sn*kp) : (cs*kc - sn*kp);
    vvs[r8][lane] = b2f(hbuf[row*CC0 + c]);
    __syncthreads();
    #pragma unroll
    for (int nn = 0; nn < 8; ++nn){
      float kk2 = krs[nn][d];
      a0 += kk2 * vvs[nn][ebase+0];
      a1 += kk2 * vvs[nn][ebase+1];
      a2 += kk2 * vvs[nn][ebase+2];
      a3 += kk2 * vvs[nn][ebase+3];
    }
    __syncthreads();
  }
  const float invN = 1.f/NPOS;
  float* kvp = kv + (((size_t)(b*NHH + h)*HDD + d)*HDD) + ebase;
  atomicAdd(kvp+0, a0*invN);
  atomicAdd(kvp+1, a1*invN);
  atomicAdd(kvp+2, a2*invN);
  atomicAdd(kvp+3, a3*invN);
}

// ---------------- fused attention ----------------
__global__ __launch_bounds__(CC0) void attn_kernel(const float* __restrict__ q,
    const float* __restrict__ kmean, const float* __restrict__ kv,
    const float* __restrict__ cosT, const float* __restrict__ sinT,
    float* __restrict__ out){
  int row = blockIdx.x;
  int tid = threadIdx.x;
  int b = row / NPOS; int n = row % NPOS;
  __shared__ float qs[CC0];
  __shared__ float qrs[NHH*33];
  __shared__ float zsh[NHH];
  qs[tid] = q[(size_t)row*CC0 + tid];
  __syncthreads();
  float pm = qs[tid] * kmean[b*CC0 + tid];
  #pragma unroll
  for (int m = 16; m >= 1; m >>= 1) pm += __shfl_xor(pm, m, 32);
  if ((tid & 31) == 0) zsh[tid >> 5] = 1.f/(pm + 1e-6f);
  int t = tid >> 1;
  float cs = cosT[(size_t)n*96 + t], sn = sinT[(size_t)n*96 + t];
  float qr = (tid & 1) ? (cs*qs[tid] + sn*qs[tid-1]) : (cs*qs[tid] - sn*qs[tid+1]);
  int hh = tid >> 5, d = tid & 31;
  qrs[hh*33 + d] = qr;
  __syncthreads();
  const float* kvp = kv + (size_t)(b*NHH + hh)*HDD*HDD;
  float acc = 0.f;
  #pragma unroll
  for (int d2 = 0; d2 < HDD; ++d2) acc += qrs[hh*33 + d2] * kvp[d2*HDD + d];
  out[(size_t)row*CC0 + tid] = acc * zsh[hh];
}

// ---------------- fused mdw dwconv + n1/n2/n3 LN chain + gelu ----------------
// 1 wave = 1 row; 4 rows/block. Lane holds 12 ch: 3 groups of 4 (c = g*256 + lane*4).
__global__ __launch_bounds__(256) void mdw_ln_kernel(const bf16* __restrict__ f1,
    const float* __restrict__ w, const float* __restrict__ bias,
    const float* __restrict__ g1, const float* __restrict__ b1,
    const float* __restrict__ g2, const float* __restrict__ b2,
    const float* __restrict__ g3, const float* __restrict__ b3,
    bf16* __restrict__ out){
  int wv = threadIdx.x >> 6, lane = threadIdx.x & 63;
  int pos = blockIdx.x*4 + wv;
  int b = pos / NPOS; int ij = pos % NPOS; int i = ij / WW; int j = ij % WW;
  size_t rowbase = (size_t)pos * C4;
  int cb = lane * 4;   // group g: channel cb + g*256

  float v[12], f[12];
  // init acc = bias
  #pragma unroll
  for (int g = 0; g < 3; ++g){
    f32x4 bv = *(const f32x4*)(bias + g*256 + cb);
    #pragma unroll
    for (int l = 0; l < 4; ++l) v[g*4+l] = bv[l];
  }
  // 9-tap dwconv
  #pragma unroll
  for (int di = 0; di < 3; ++di){
    int ii = i + di - 1;
    if (ii < 0 || ii >= HH) continue;
    #pragma unroll
    for (int dj = 0; dj < 3; ++dj){
      int jj = j + dj - 1;
      if (jj < 0 || jj >= WW) continue;
      size_t off = ((size_t)b*NPOS + ii*WW + jj)*C4;
      const float* wp = w + (di*3 + dj)*C4;
      #pragma unroll
      for (int g = 0; g < 3; ++g){
        int c = g*256 + cb;
        short4v x = *(const short4v*)((const short*)f1 + off + c);
        f32x4 wv4 = *(const f32x4*)(wp + c);
        #pragma unroll
        for (int l = 0; l < 4; ++l) v[g*4+l] += s2f(x[l]) * wv4[l];
      }
    }
  }
  // f1 (center row) + add
  #pragma unroll
  for (int g = 0; g < 3; ++g){
    int c = g*256 + cb;
    short4v x = *(const short4v*)((const short*)f1 + rowbase + c);
    #pragma unroll
    for (int l = 0; l < 4; ++l){ f[g*4+l] = s2f(x[l]); v[g*4+l] += f[g*4+l]; }
  }
  // 3 chained LNs (wave-local reductions, no barriers)
  const float* gs[3] = {g1, g2, g3};
  const float* bs[3] = {b1, b2, b3};
  #pragma unroll
  for (int pass = 0; pass < 3; ++pass){
    float s = 0.f, q = 0.f;
    #pragma unroll
    for (int l = 0; l < 12; ++l){ s += v[l]; q += v[l]*v[l]; }
    #pragma unroll
    for (int m = 1; m < 64; m <<= 1){ s += __shfl_xor(s, m, 64); q += __shfl_xor(q, m, 64); }
    float mean = s * (1.f/C4);
    float rstd = rsqrtf(q * (1.f/C4) - mean*mean + 1e-5f);
    #pragma unroll
    for (int g = 0; g < 3; ++g){
      int c = g*256 + cb;
      f32x4 gv = *(const f32x4*)(gs[pass] + c);
      f32x4 bv = *(const f32x4*)(bs[pass] + c);
      #pragma unroll
      for (int l = 0; l < 4; ++l){
        int e = g*4 + l;
        v[e] = (v[e]-mean)*rstd*gv[l] + bv[l];
        if (pass < 2) v[e] += f[e];
      }
    }
  }
  // gelu + store
  #pragma unroll
  for (int g = 0; g < 3; ++g){
    short4v o;
    #pragma unroll
    for (int l = 0; l < 4; ++l) o[l] = f2s(fast_gelu(v[g*4+l]));
    *(short4v*)((short*)out + rowbase + g*256 + cb) = o;
  }
}

extern "C" void kernel_launch(void* const* d_in, const int* in_sizes, int n_in,
                              void* d_out, int out_size, void* d_ws, size_t ws_size,
                              hipStream_t stream){
  (void)in_sizes; (void)n_in; (void)out_size; (void)ws_size;
  const float* X      = (const float*)d_in[0];
  const float* cpe1_w = (const float*)d_in[1];
  const float* cpe1_b = (const float*)d_in[2];
  const float* n1g    = (const float*)d_in[3];
  const float* n1b    = (const float*)d_in[4];
  const float* in_w   = (const float*)d_in[5];
  const float* in_b   = (const float*)d_in[6];
  const float* actp_w = (const float*)d_in[7];
  const float* actp_b = (const float*)d_in[8];
  const float* dwc_w  = (const float*)d_in[9];
  const float* dwc_b  = (const float*)d_in[10];
  const float* qk_w   = (const float*)d_in[11];
  const float* qk_b   = (const float*)d_in[12];
  const float* lepe_w = (const float*)d_in[13];
  const float* lepe_b = (const float*)d_in[14];
  const float* outp_w = (const float*)d_in[15];
  const float* outp_b = (const float*)d_in[16];
  const float* cpe2_w = (const float*)d_in[17];
  const float* cpe2_b = (const float*)d_in[18];
  const float* n2g    = (const float*)d_in[19];
  const float* n2b    = (const float*)d_in[20];
  const float* fc1_w  = (const float*)d_in[21];
  const float* fc1_b  = (const float*)d_in[22];
  const float* mdw_w  = (const float*)d_in[23];
  const float* mdw_b  = (const float*)d_in[24];
  const float* fc2_w  = (const float*)d_in[25];
  const float* fc2_b  = (const float*)d_in[26];
  const float* mn1g   = (const float*)d_in[27];
  const float* mn1b   = (const float*)d_in[28];
  const float* mn2g   = (const float*)d_in[29];
  const float* mn2b   = (const float*)d_in[30];
  const float* mn3g   = (const float*)d_in[31];
  const float* mn3b   = (const float*)d_in[32];

  char* ws = (char*)d_ws;
  const size_t SZF = (size_t)MROWS*CC0*4;
  const size_t SZB = (size_t)MROWS*CC0*2;
  float* A0 = (float*)(ws);                 // x1 -> x3
  float* A1 = (float*)(ws + 1*SZF);         // q -> x2
  float* A2 = (float*)(ws + 2*SZF);         // k -> attn(+lepe)
  bf16*  B0 = (bf16*)(ws + 3*SZF);          // xn -> xm
  bf16*  B1 = (bf16*)(ws + 3*SZF + 1*SZB);  // act_res
  bf16*  B2 = (bf16*)(ws + 3*SZF + 2*SZB);  // t
  bf16*  B3 = (bf16*)(ws + 3*SZF + 3*SZB);  // h
  bf16*  F1 = (bf16*)(ws + 1*SZF);          // f1 (spans A1+A2; both dead)
  bf16*  DW = (bf16*)(ws + 3*SZF);          // gelu(n3) (spans B0..B3; dead)
  char* tail = ws + 3*SZF + 4*SZB;
  float* KMEAN = (float*)tail;                 tail += (size_t)BB*CC0*4;
  float* KV    = (float*)tail;                 tail += (size_t)BB*NHH*HDD*HDD*4;
  float* COS   = (float*)tail;                 tail += (size_t)NPOS*96*4;
  float* SIN   = (float*)tail;

  const int G192F = (MROWS*(CC0/4))/256;
  const int G192B = (MROWS*(CC0/8))/256;

  // 1. x1 = x + cpe1(x)
  dwconv_v<float,CC0,0><<<G192F, 256, 0, stream>>>(X, cpe1_w, cpe1_b, A0);
  rope_tables_kernel<<<(NPOS*96 + 255)/256, 256, 0, stream>>>(COS, SIN);
  // 2. xn = LN(x1)
  ln192_kernel<<<MROWS, 64, 0, stream>>>(A0, n1g, n1b, B0);
  // 3. act_res = silu(xn@actp)
  mfma_gemm<CC0,CC0,0,1><<<dim3(MROWS/BM,CC0/BN), 256, 0, stream>>>(B0, nullptr, actp_w, actp_b, nullptr, B1, nullptr);
  // 4. t = xn@in_w + b
  mfma_gemm<CC0,CC0,0,0><<<dim3(MROWS/BM,CC0/BN), 256, 0, stream>>>(B0, nullptr, in_w, in_b, nullptr, B2, nullptr);
  // 5. h = silu(dwc(t))
  dwconv_v<bf16,CC0,1><<<G192B, 256, 0, stream>>>(B2, dwc_w, dwc_b, B3);
  // 6. qk = h@qk_w; q->A1, k->A2
  mfma_gemm<CC0,2*CC0,0,2><<<dim3(MROWS/BM,2*CC0/BN), 256, 0, stream>>>(B3, nullptr, qk_w, qk_b, nullptr, A1, A2);
  // 7. kmean, kv
  hipMemsetAsync(KMEAN, 0, (size_t)BB*CC0*4, stream);
  hipMemsetAsync(KV, 0, (size_t)BB*NHH*HDD*HDD*4, stream);
  kmean_kernel<<<BB*7, CC0, 0, stream>>>(A2, KMEAN);
  kv_kernel<<<BB*NHH*14, 256, 0, stream>>>(A2, B3, COS, SIN, KV);
  // 8. attn core -> A2
  attn_kernel<<<MROWS, CC0, 0, stream>>>(A1, KMEAN, KV, COS, SIN, A2);
  // 9. attn += lepe(h)
  dwconv_v<bf16,CC0,2><<<G192B, 256, 0, stream>>>(B3, lepe_w, lepe_b, A2);
  // 10. x2 = x1 + (attn*act_res)@outp + b -> A1
  mfma_gemm<CC0,CC0,1,3><<<dim3(MROWS/BM,CC0/BN), 256, 0, stream>>>(A2, B1, outp_w, outp_b, A0, A1, nullptr);
  // 11. x3 = x2 + cpe2(x2) -> A0
  dwconv_v<float,CC0,0><<<G192F, 256, 0, stream>>>(A1, cpe2_w, cpe2_b, A0);
  // 12. xm = LN(x3) -> B0
  ln192_kernel<<<MROWS, 64, 0, stream>>>(A0, n2g, n2b, B0);
  // 13. f1 = xm@fc1 + b -> F1
  mfma_gemm<CC0,C4,0,0><<<dim3(MROWS/BM,C4/BN), 256, 0, stream>>>(B0, nullptr, fc1_w, fc1_b, nullptr, F1, nullptr);
  // 14+15. fused: dw = mdw(f1); n1..n3 chained LN; gelu -> DW
  mdw_ln_kernel<<<MROWS/4, 256, 0, stream>>>(F1, mdw_w, mdw_b, mn1g, mn1b, mn2g, mn2b, mn3g, mn3b, DW);
  // 16. out = x3 + gelu(n3)@fc2 + b (f32)
  mfma_gemm<C4,CC0,0,3><<<dim3(MROWS/BM,CC0/BN), 256, 0, stream>>>(DW, nullptr, fc2_w, fc2_b, A0, d_out, nullptr);
}

// Round 6
// 722.834 us; speedup vs baseline: 3.1936x; 1.1576x over previous
//
#include <hip/hip_runtime.h>
#include <hip/hip_bf16.h>
#include <math.h>

#define BB 16
#define HH 56
#define WW 56
#define CC0 192
#define NHH 6
#define HDD 32
#define NPOS (HH*WW)       // 3136
#define MROWS (BB*NPOS)    // 50176
#define C4 (4*CC0)         // 768

typedef __hip_bfloat16 bf16;
typedef short short8 __attribute__((ext_vector_type(8)));
typedef short short4v __attribute__((ext_vector_type(4)));
typedef float f32x4 __attribute__((ext_vector_type(4)));

__device__ __forceinline__ float b2f(bf16 v){ return __bfloat162float(v); }
__device__ __forceinline__ bf16 f2b(float v){ return __float2bfloat16(v); }
__device__ __forceinline__ short f2s(float v){ bf16 b = __float2bfloat16(v); return *(short*)&b; }
__device__ __forceinline__ float s2f(short s){ bf16 b; *(short*)&b = s; return __bfloat162float(b); }
__device__ __forceinline__ float fast_gelu(float x){
  float u = 1.5957691216f * (x + 0.044715f*x*x*x);
  float t = 1.f - 2.f/(__expf(u) + 1.f);
  return 0.5f*x*(1.f + t);
}

// ---------------- weight pre-convert: f32 [K][N] -> bf16 W^T [N][K] ----------------
// segments (elems): actp 36864 | in 36864 | qk 73728 | outp 36864 | fc1 147456 | fc2 147456
__global__ __launch_bounds__(256) void convert_weights(
    const float* __restrict__ w0, const float* __restrict__ w1,
    const float* __restrict__ w2, const float* __restrict__ w3,
    const float* __restrict__ w4, const float* __restrict__ w5,
    short* __restrict__ dst){
  int t = blockIdx.x*256 + threadIdx.x;
  int e = t*4;
  if (e >= 479232) return;
  const float* src; int K, N, off;
  if      (e <  36864){ src=w0; K=192; N=192; off=0; }
  else if (e <  73728){ src=w1; K=192; N=192; off=36864; }
  else if (e < 147456){ src=w2; K=192; N=384; off=73728; }
  else if (e < 184320){ src=w3; K=192; N=192; off=147456; }
  else if (e < 331776){ src=w4; K=192; N=768; off=184320; }
  else                { src=w5; K=768; N=192; off=331776; }
  int le = e - off;
  int n = le / K, k = le % K;
  short4v o;
  #pragma unroll
  for (int l = 0; l < 4; ++l) o[l] = f2s(src[(size_t)(k+l)*N + n]);
  *(short4v*)(dst + e) = o;
}

// ---------------- vectorized depthwise 3x3 conv ----------------
// MODE 0: out(f32) = in(f32) + conv+bias     (cpe1/cpe2)
// MODE 1: out(bf16) = silu(conv+bias)        (dwc, in bf16)
// MODE 2: out(bf16) += conv+bias             (lepe, in bf16, bf16 RMW)
template<typename TIN, int CC, int MODE>
__global__ __launch_bounds__(256) void dwconv_v(const TIN* __restrict__ in,
    const float* __restrict__ w, const float* __restrict__ bias, void* __restrict__ out){
  constexpr int VEC = 16 / (int)sizeof(TIN);
  constexpr int NG = CC / VEC;
  int idx = blockIdx.x*256 + threadIdx.x;
  int cg = idx % NG; int pos = idx / NG;
  int b = pos / NPOS; int ij = pos % NPOS; int i = ij / WW; int j = ij % WW;
  int cb = cg * VEC;
  float acc[VEC];
  #pragma unroll
  for (int l = 0; l < VEC; ++l) acc[l] = bias[cb + l];
  #pragma unroll
  for (int di = 0; di < 3; ++di){
    int ii = i + di - 1;
    if (ii < 0 || ii >= HH) continue;
    #pragma unroll
    for (int dj = 0; dj < 3; ++dj){
      int jj = j + dj - 1;
      if (jj < 0 || jj >= WW) continue;
      size_t off = ((size_t)b*NPOS + ii*WW + jj)*CC + cb;
      const float* wp = w + (di*3 + dj)*CC + cb;
      if constexpr (sizeof(TIN) == 2){
        short8 v = *(const short8*)((const short*)in + off);
        #pragma unroll
        for (int l = 0; l < 8; ++l) acc[l] += s2f(v[l]) * wp[l];
      } else {
        f32x4 v = *(const f32x4*)((const float*)in + off);
        #pragma unroll
        for (int l = 0; l < 4; ++l) acc[l] += v[l] * wp[l];
      }
    }
  }
  size_t oidx = (size_t)pos*CC + cb;
  if constexpr (MODE == 0){
    f32x4 r = *(const f32x4*)((const float*)in + oidx);
    f32x4 o;
    #pragma unroll
    for (int l = 0; l < 4; ++l) o[l] = r[l] + acc[l];
    *(f32x4*)((float*)out + oidx) = o;
  } else if constexpr (MODE == 1){
    short8 o;
    #pragma unroll
    for (int l = 0; l < 8; ++l){ float s = acc[l]/(1.f + expf(-acc[l])); o[l] = f2s(s); }
    *(short8*)((short*)out + oidx) = o;
  } else {
    short* op = (short*)out + oidx;
    short8 r = *(short8*)op;
    short8 o;
    #pragma unroll
    for (int l = 0; l < 8; ++l) o[l] = f2s(s2f(r[l]) + acc[l]);
    *(short8*)op = o;
  }
}

// ---------------- LayerNorm over C=192 (f32 in, bf16 out) ----------------
__global__ __launch_bounds__(64) void ln192_kernel(const float* __restrict__ x,
    const float* __restrict__ g, const float* __restrict__ bb, bf16* __restrict__ out){
  int row = blockIdx.x; int t = threadIdx.x;
  const float* xr = x + (size_t)row*CC0;
  float v0 = xr[t], v1 = xr[t+64], v2 = xr[t+128];
  float s = v0+v1+v2;
  float q = v0*v0+v1*v1+v2*v2;
  #pragma unroll
  for (int m = 1; m < 64; m <<= 1){ s += __shfl_xor(s, m, 64); q += __shfl_xor(q, m, 64); }
  float mean = s * (1.f/CC0);
  float rstd = rsqrtf(q * (1.f/CC0) - mean*mean + 1e-5f);
  bf16* orow = out + (size_t)row*CC0;
  orow[t]     = f2b((v0-mean)*rstd*g[t]     + bb[t]);
  orow[t+64]  = f2b((v1-mean)*rstd*g[t+64]  + bb[t+64]);
  orow[t+128] = f2b((v2-mean)*rstd*g[t+128] + bb[t+128]);
}

// ---------------- MFMA GEMM: A [M,K] bf16-ish @ W^T [N,K] bf16 + bias ----------------
// ALOAD: 0 = bf16 direct, 1 = bf16 * bf16 product
// EPI: 0 = bf16, 1 = silu->bf16, 2 = elu+1 split ->bf16, 3 = +addf(f32) ->f32
#define BM 256
#define BN 64
#define BK 32
#define LDA 40
template<int K, int N, int ALOAD, int EPI>
__global__ __launch_bounds__(256) void mfma_gemm(
    const void* __restrict__ a0v, const void* __restrict__ a1v,
    const short* __restrict__ wT, const float* __restrict__ bias,
    const float* __restrict__ addf, void* __restrict__ out0, void* __restrict__ out1){
  __shared__ short As[BM*LDA];
  __shared__ short Bs[BN*LDA];
  int tid = threadIdx.x;
  int wave = tid >> 6, lane = tid & 63;
  size_t m0 = (size_t)blockIdx.x * BM;
  int n0 = blockIdx.y * BN;
  int wm = wave * 64;
  int am = lane & 15, ak = (lane >> 4) * 8;

  f32x4 acc[4][4];
  #pragma unroll
  for (int mt = 0; mt < 4; ++mt)
    #pragma unroll
    for (int nt = 0; nt < 4; ++nt)
      acc[mt][nt] = (f32x4){0.f,0.f,0.f,0.f};

  for (int k0 = 0; k0 < K; k0 += BK){
    // ---- stage A (BM x BK) ----
    if constexpr (ALOAD == 0){
      const short* A = (const short*)a0v;
      #pragma unroll
      for (int it = 0; it < 4; ++it){
        int idx = it*256 + tid;
        int row = idx >> 2; int ko = (idx & 3) * 8;
        short8 v = *(const short8*)(A + (m0 + row)*(size_t)K + k0 + ko);
        *(short8*)&As[row*LDA + ko] = v;
      }
    } else {
      const short* A0p = (const short*)a0v;
      const short* A1p = (const short*)a1v;
      #pragma unroll
      for (int it = 0; it < 4; ++it){
        int idx = it*256 + tid;
        int row = idx >> 2; int ko = (idx & 3) * 8;
        size_t off = (m0 + row)*(size_t)K + k0 + ko;
        short8 va = *(const short8*)(A0p + off);
        short8 vb = *(const short8*)(A1p + off);
        short8 o;
        #pragma unroll
        for (int l = 0; l < 8; ++l) o[l] = f2s(s2f(va[l]) * s2f(vb[l]));
        *(short8*)&As[row*LDA + ko] = o;
      }
    }
    // ---- stage B (BN x BK) from W^T ----
    {
      int row = tid >> 2; int ko = (tid & 3) * 8;
      short8 v = *(const short8*)(wT + (size_t)(n0 + row)*K + k0 + ko);
      *(short8*)&Bs[row*LDA + ko] = v;
    }
    __syncthreads();
    short8 af[4], bfr[4];
    #pragma unroll
    for (int mt = 0; mt < 4; ++mt) af[mt] = *(short8*)&As[(wm + mt*16 + am)*LDA + ak];
    #pragma unroll
    for (int nt = 0; nt < 4; ++nt) bfr[nt] = *(short8*)&Bs[(nt*16 + am)*LDA + ak];
    #pragma unroll
    for (int mt = 0; mt < 4; ++mt)
      #pragma unroll
      for (int nt = 0; nt < 4; ++nt)
        acc[mt][nt] = __builtin_amdgcn_mfma_f32_16x16x32_bf16(af[mt], bfr[nt], acc[mt][nt], 0, 0, 0);
    __syncthreads();
  }

  int cn = lane & 15;
  int cr = (lane >> 4) * 4;
  #pragma unroll
  for (int mt = 0; mt < 4; ++mt){
    #pragma unroll
    for (int nt = 0; nt < 4; ++nt){
      int gn = n0 + nt*16 + cn;
      float bv = bias[gn];
      #pragma unroll
      for (int r = 0; r < 4; ++r){
        size_t gm = m0 + wm + mt*16 + cr + r;
        float v = acc[mt][nt][r] + bv;
        if constexpr (EPI == 0){
          ((bf16*)out0)[gm*N + gn] = f2b(v);
        } else if constexpr (EPI == 1){
          ((bf16*)out0)[gm*N + gn] = f2b(v / (1.f + expf(-v)));
        } else if constexpr (EPI == 2){
          float rv = (v > 0.f) ? (v + 1.f) : expf(v);
          if (n0 < CC0) ((bf16*)out0)[gm*CC0 + gn] = f2b(rv);
          else          ((bf16*)out1)[gm*CC0 + (gn - CC0)] = f2b(rv);
        } else {
          ((float*)out0)[gm*N + gn] = addf[gm*N + gn] + v;
        }
      }
    }
  }
}

// ---------------- RoPE tables (H,W,96) ----------------
__global__ void rope_tables_kernel(float* __restrict__ cosT, float* __restrict__ sinT){
  int idx = blockIdx.x*256 + threadIdx.x;
  if (idx >= NPOS*96) return;
  int t = idx % 96; int ij = idx / 96; int i = ij / WW; int j = ij % WW;
  int kk = (t < 48) ? t : (t - 48);
  float th = expf(-(float)kk * 0.19188209108283716f);
  float pos = (t < 48) ? (float)i : (float)j;
  float ang = pos * th;
  cosT[idx] = cosf(ang);
  sinT[idx] = sinf(ang);
}

// ---------------- kmean (k in bf16) ----------------
__global__ __launch_bounds__(CC0) void kmean_kernel(const bf16* __restrict__ k, float* __restrict__ kmean){
  int b = blockIdx.x / 7; int chunk = blockIdx.x % 7; int c = threadIdx.x;
  const bf16* kp = k + ((size_t)b*NPOS + (size_t)chunk*448)*CC0 + c;
  float s = 0.f;
  for (int r = 0; r < 448; ++r) s += b2f(kp[(size_t)r*CC0]);
  atomicAdd(&kmean[b*CC0 + c], s * (1.f/NPOS));
}

// ---------------- kv (k, h in bf16) ----------------
__global__ __launch_bounds__(256) void kv_kernel(const bf16* __restrict__ kbuf,
    const bf16* __restrict__ hbuf, const float* __restrict__ cosT,
    const float* __restrict__ sinT, float* __restrict__ kv){
  int bi = blockIdx.x;
  int chunk = bi % 14; bi /= 14;
  int h = bi % NHH; int b = bi / NHH;
  int tid = threadIdx.x;
  int r8 = tid >> 5, lane = tid & 31;
  __shared__ float krs[8][32];
  __shared__ float vvs[8][32];
  int d = tid >> 3; int ebase = (tid & 7) * 4;
  float a0 = 0.f, a1 = 0.f, a2 = 0.f, a3 = 0.f;
  int c = h*HDD + lane;
  int t = c >> 1;
  bool odd = (lane & 1);
  for (int step = 0; step < 28; ++step){
    int n = chunk*224 + step*8 + r8;
    size_t row = (size_t)b*NPOS + n;
    float kc = b2f(kbuf[row*CC0 + c]);
    float kp = b2f(kbuf[row*CC0 + (c ^ 1)]);
    float cs = cosT[(size_t)n*96 + t], sn = sinT[(size_t)n*96 + t];
    krs[r8][lane] = odd ? (cs*kc + sn*kp) : (cs*kc - sn*kp);
    vvs[r8][lane] = b2f(hbuf[row*CC0 + c]);
    __syncthreads();
    #pragma unroll
    for (int nn = 0; nn < 8; ++nn){
      float kk2 = krs[nn][d];
      a0 += kk2 * vvs[nn][ebase+0];
      a1 += kk2 * vvs[nn][ebase+1];
      a2 += kk2 * vvs[nn][ebase+2];
      a3 += kk2 * vvs[nn][ebase+3];
    }
    __syncthreads();
  }
  const float invN = 1.f/NPOS;
  float* kvp = kv + (((size_t)(b*NHH + h)*HDD + d)*HDD) + ebase;
  atomicAdd(kvp+0, a0*invN);
  atomicAdd(kvp+1, a1*invN);
  atomicAdd(kvp+2, a2*invN);
  atomicAdd(kvp+3, a3*invN);
}

// ---------------- fused attention (q bf16 in, attn bf16 out) ----------------
__global__ __launch_bounds__(CC0) void attn_kernel(const bf16* __restrict__ q,
    const float* __restrict__ kmean, const float* __restrict__ kv,
    const float* __restrict__ cosT, const float* __restrict__ sinT,
    bf16* __restrict__ out){
  int row = blockIdx.x;
  int tid = threadIdx.x;
  int b = row / NPOS; int n = row % NPOS;
  __shared__ float qs[CC0];
  __shared__ float qrs[NHH*33];
  __shared__ float zsh[NHH];
  qs[tid] = b2f(q[(size_t)row*CC0 + tid]);
  __syncthreads();
  float pm = qs[tid] * kmean[b*CC0 + tid];
  #pragma unroll
  for (int m = 16; m >= 1; m >>= 1) pm += __shfl_xor(pm, m, 32);
  if ((tid & 31) == 0) zsh[tid >> 5] = 1.f/(pm + 1e-6f);
  int t = tid >> 1;
  float cs = cosT[(size_t)n*96 + t], sn = sinT[(size_t)n*96 + t];
  float qr = (tid & 1) ? (cs*qs[tid] + sn*qs[tid-1]) : (cs*qs[tid] - sn*qs[tid+1]);
  int hh = tid >> 5, d = tid & 31;
  qrs[hh*33 + d] = qr;
  __syncthreads();
  const float* kvp = kv + (size_t)(b*NHH + hh)*HDD*HDD;
  float acc = 0.f;
  #pragma unroll
  for (int d2 = 0; d2 < HDD; ++d2) acc += qrs[hh*33 + d2] * kvp[d2*HDD + d];
  out[(size_t)row*CC0 + tid] = f2b(acc * zsh[hh]);
}

// ---------------- fused mdw dwconv + n1/n2/n3 LN chain + gelu ----------------
// 1 wave = 1 row; 4 rows/block. Lane holds 12 ch: short8 at c0=lane*8, short4 at c1=512+lane*4.
__global__ __launch_bounds__(256) void mdw_ln_kernel(const bf16* __restrict__ f1,
    const float* __restrict__ w, const float* __restrict__ bias,
    const float* __restrict__ g1, const float* __restrict__ b1,
    const float* __restrict__ g2, const float* __restrict__ b2,
    const float* __restrict__ g3, const float* __restrict__ b3,
    bf16* __restrict__ out){
  int wv = threadIdx.x >> 6, lane = threadIdx.x & 63;
  int pos = blockIdx.x*4 + wv;
  int b = pos / NPOS; int ij = pos % NPOS; int i = ij / WW; int j = ij % WW;
  size_t rowbase = (size_t)pos * C4;
  int c0 = lane * 8;        // channels c0..c0+7
  int c1 = 512 + lane * 4;  // channels c1..c1+3

  float v[12], f[12];
  {
    f32x4 bv0 = *(const f32x4*)(bias + c0);
    f32x4 bv1 = *(const f32x4*)(bias + c0 + 4);
    f32x4 bv2 = *(const f32x4*)(bias + c1);
    #pragma unroll
    for (int l = 0; l < 4; ++l){ v[l] = bv0[l]; v[4+l] = bv1[l]; v[8+l] = bv2[l]; }
  }
  #pragma unroll
  for (int di = 0; di < 3; ++di){
    int ii = i + di - 1;
    if (ii < 0 || ii >= HH) continue;
    #pragma unroll
    for (int dj = 0; dj < 3; ++dj){
      int jj = j + dj - 1;
      if (jj < 0 || jj >= WW) continue;
      size_t off = ((size_t)b*NPOS + ii*WW + jj)*C4;
      const float* wp = w + (di*3 + dj)*C4;
      short8 x0 = *(const short8*)((const short*)f1 + off + c0);
      short4v x1 = *(const short4v*)((const short*)f1 + off + c1);
      f32x4 w0 = *(const f32x4*)(wp + c0);
      f32x4 w1 = *(const f32x4*)(wp + c0 + 4);
      f32x4 w2 = *(const f32x4*)(wp + c1);
      #pragma unroll
      for (int l = 0; l < 4; ++l){
        v[l]   += s2f(x0[l])   * w0[l];
        v[4+l] += s2f(x0[4+l]) * w1[l];
        v[8+l] += s2f(x1[l])   * w2[l];
      }
    }
  }
  {
    short8 x0 = *(const short8*)((const short*)f1 + rowbase + c0);
    short4v x1 = *(const short4v*)((const short*)f1 + rowbase + c1);
    #pragma unroll
    for (int l = 0; l < 8; ++l){ f[l] = s2f(x0[l]); v[l] += f[l]; }
    #pragma unroll
    for (int l = 0; l < 4; ++l){ f[8+l] = s2f(x1[l]); v[8+l] += f[8+l]; }
  }
  const float* gs[3] = {g1, g2, g3};
  const float* bs[3] = {b1, b2, b3};
  #pragma unroll
  for (int pass = 0; pass < 3; ++pass){
    float s = 0.f, q = 0.f;
    #pragma unroll
    for (int l = 0; l < 12; ++l){ s += v[l]; q += v[l]*v[l]; }
    #pragma unroll
    for (int m = 1; m < 64; m <<= 1){ s += __shfl_xor(s, m, 64); q += __shfl_xor(q, m, 64); }
    float mean = s * (1.f/C4);
    float rstd = rsqrtf(q * (1.f/C4) - mean*mean + 1e-5f);
    f32x4 g0 = *(const f32x4*)(gs[pass] + c0);
    f32x4 g1v = *(const f32x4*)(gs[pass] + c0 + 4);
    f32x4 g2v = *(const f32x4*)(gs[pass] + c1);
    f32x4 bb0 = *(const f32x4*)(bs[pass] + c0);
    f32x4 bb1 = *(const f32x4*)(bs[pass] + c0 + 4);
    f32x4 bb2 = *(const f32x4*)(bs[pass] + c1);
    #pragma unroll
    for (int l = 0; l < 4; ++l){
      v[l]   = (v[l]  -mean)*rstd*g0[l]  + bb0[l];
      v[4+l] = (v[4+l]-mean)*rstd*g1v[l] + bb1[l];
      v[8+l] = (v[8+l]-mean)*rstd*g2v[l] + bb2[l];
    }
    if (pass < 2){
      #pragma unroll
      for (int l = 0; l < 12; ++l) v[l] += f[l];
    }
  }
  short8 o0; short4v o1;
  #pragma unroll
  for (int l = 0; l < 8; ++l) o0[l] = f2s(fast_gelu(v[l]));
  #pragma unroll
  for (int l = 0; l < 4; ++l) o1[l] = f2s(fast_gelu(v[8+l]));
  *(short8*)((short*)out + rowbase + c0) = o0;
  *(short4v*)((short*)out + rowbase + c1) = o1;
}

extern "C" void kernel_launch(void* const* d_in, const int* in_sizes, int n_in,
                              void* d_out, int out_size, void* d_ws, size_t ws_size,
                              hipStream_t stream){
  (void)in_sizes; (void)n_in; (void)out_size; (void)ws_size;
  const float* X      = (const float*)d_in[0];
  const float* cpe1_w = (const float*)d_in[1];
  const float* cpe1_b = (const float*)d_in[2];
  const float* n1g    = (const float*)d_in[3];
  const float* n1b    = (const float*)d_in[4];
  const float* in_w   = (const float*)d_in[5];
  const float* in_b   = (const float*)d_in[6];
  const float* actp_w = (const float*)d_in[7];
  const float* actp_b = (const float*)d_in[8];
  const float* dwc_w  = (const float*)d_in[9];
  const float* dwc_b  = (const float*)d_in[10];
  const float* qk_w   = (const float*)d_in[11];
  const float* qk_b   = (const float*)d_in[12];
  const float* lepe_w = (const float*)d_in[13];
  const float* lepe_b = (const float*)d_in[14];
  const float* outp_w = (const float*)d_in[15];
  const float* outp_b = (const float*)d_in[16];
  const float* cpe2_w = (const float*)d_in[17];
  const float* cpe2_b = (const float*)d_in[18];
  const float* n2g    = (const float*)d_in[19];
  const float* n2b    = (const float*)d_in[20];
  const float* fc1_w  = (const float*)d_in[21];
  const float* fc1_b  = (const float*)d_in[22];
  const float* mdw_w  = (const float*)d_in[23];
  const float* mdw_b  = (const float*)d_in[24];
  const float* fc2_w  = (const float*)d_in[25];
  const float* fc2_b  = (const float*)d_in[26];
  const float* mn1g   = (const float*)d_in[27];
  const float* mn1b   = (const float*)d_in[28];
  const float* mn2g   = (const float*)d_in[29];
  const float* mn2b   = (const float*)d_in[30];
  const float* mn3g   = (const float*)d_in[31];
  const float* mn3b   = (const float*)d_in[32];

  char* ws = (char*)d_ws;
  const size_t SZF = (size_t)MROWS*CC0*4;   // 38.5 MB
  const size_t SZB = (size_t)MROWS*CC0*2;   // 19.3 MB
  float* A0 = (float*)(ws);                 // x1 -> x3 (f32 residual spine)
  char* base2 = ws + SZF;
  bf16* BQ = (bf16*)(base2 + 0*SZB);        // q
  bf16* BKb= (bf16*)(base2 + 1*SZB);        // k
  bf16* BA = (bf16*)(base2 + 2*SZB);        // attn (+lepe)
  bf16* B1 = (bf16*)(base2 + 3*SZB);        // act_res
  bf16* B0 = (bf16*)(base2 + 4*SZB);        // xn -> xm
  bf16* B2 = (bf16*)(base2 + 5*SZB);        // t
  bf16* B3 = (bf16*)(base2 + 6*SZB);        // h
  // slot 7 = spare for DW's 4th quarter
  float* A1 = (float*)(base2);              // x2 (f32) overlays BQ+BK (dead by step 10)
  bf16*  F1 = (bf16*)(base2);               // f1 overlays slots 0-3 (dead by step 13)
  bf16*  DW = (bf16*)(base2 + 4*SZB);       // gelu(n3) overlays slots 4-7 (dead by step 14)
  short* WT = (short*)(base2 + 8*SZB);      // converted weights (479232 shorts)
  char* tail = (char*)(WT + 479232 + 64);
  float* KMEAN = (float*)tail;                 tail += (size_t)BB*CC0*4;
  float* KV    = (float*)tail;                 tail += (size_t)BB*NHH*HDD*HDD*4;
  float* COS   = (float*)tail;                 tail += (size_t)NPOS*96*4;
  float* SIN   = (float*)tail;

  const short* actpT = WT + 0;
  const short* inT   = WT + 36864;
  const short* qkT   = WT + 73728;
  const short* outpT = WT + 147456;
  const short* fc1T  = WT + 184320;
  const short* fc2T  = WT + 331776;

  const int G192F = (MROWS*(CC0/4))/256;
  const int G192B = (MROWS*(CC0/8))/256;

  // 0. weight pre-convert (f32 -> bf16 W^T)
  convert_weights<<<(479232/4 + 255)/256, 256, 0, stream>>>(actp_w, in_w, qk_w, outp_w, fc1_w, fc2_w, WT);
  rope_tables_kernel<<<(NPOS*96 + 255)/256, 256, 0, stream>>>(COS, SIN);
  // 1. x1 = x + cpe1(x)
  dwconv_v<float,CC0,0><<<G192F, 256, 0, stream>>>(X, cpe1_w, cpe1_b, A0);
  // 2. xn = LN(x1)
  ln192_kernel<<<MROWS, 64, 0, stream>>>(A0, n1g, n1b, B0);
  // 3. act_res = silu(xn@actp)
  mfma_gemm<CC0,CC0,0,1><<<dim3(MROWS/BM,CC0/BN), 256, 0, stream>>>(B0, nullptr, actpT, actp_b, nullptr, B1, nullptr);
  // 4. t = xn@in_w + b
  mfma_gemm<CC0,CC0,0,0><<<dim3(MROWS/BM,CC0/BN), 256, 0, stream>>>(B0, nullptr, inT, in_b, nullptr, B2, nullptr);
  // 5. h = silu(dwc(t))
  dwconv_v<bf16,CC0,1><<<G192B, 256, 0, stream>>>(B2, dwc_w, dwc_b, B3);
  // 6. qk = h@qk_w; q->BQ, k->BK (bf16, elu+1)
  mfma_gemm<CC0,2*CC0,0,2><<<dim3(MROWS/BM,2*CC0/BN), 256, 0, stream>>>(B3, nullptr, qkT, qk_b, nullptr, BQ, BKb);
  // 7. kmean, kv
  hipMemsetAsync(KMEAN, 0, (size_t)BB*CC0*4, stream);
  hipMemsetAsync(KV, 0, (size_t)BB*NHH*HDD*HDD*4, stream);
  kmean_kernel<<<BB*7, CC0, 0, stream>>>(BKb, KMEAN);
  kv_kernel<<<BB*NHH*14, 256, 0, stream>>>(BKb, B3, COS, SIN, KV);
  // 8. attn core -> BA (bf16)
  attn_kernel<<<MROWS, CC0, 0, stream>>>(BQ, KMEAN, KV, COS, SIN, BA);
  // 9. attn += lepe(h) (bf16 RMW)
  dwconv_v<bf16,CC0,2><<<G192B, 256, 0, stream>>>(B3, lepe_w, lepe_b, BA);
  // 10. x2 = x1 + (attn*act_res)@outp + b -> A1 (f32; overlays q/k, both dead)
  mfma_gemm<CC0,CC0,1,3><<<dim3(MROWS/BM,CC0/BN), 256, 0, stream>>>(BA, B1, outpT, outp_b, A0, A1, nullptr);
  // 11. x3 = x2 + cpe2(x2) -> A0
  dwconv_v<float,CC0,0><<<G192F, 256, 0, stream>>>(A1, cpe2_w, cpe2_b, A0);
  // 12. xm = LN(x3) -> B0
  ln192_kernel<<<MROWS, 64, 0, stream>>>(A0, n2g, n2b, B0);
  // 13. f1 = xm@fc1 + b -> F1 (overlays slots 0-3, all dead)
  mfma_gemm<CC0,C4,0,0><<<dim3(MROWS/BM,C4/BN), 256, 0, stream>>>(B0, nullptr, fc1T, fc1_b, nullptr, F1, nullptr);
  // 14. fused: mdw conv + n1..n3 LN chain + gelu -> DW (overlays slots 4-7)
  mdw_ln_kernel<<<MROWS/4, 256, 0, stream>>>(F1, mdw_w, mdw_b, mn1g, mn1b, mn2g, mn2b, mn3g, mn3b, DW);
  // 15. out = x3 + gelu(n3)@fc2 + b (f32)
  mfma_gemm<C4,CC0,0,3><<<dim3(MROWS/BM,CC0/BN), 256, 0, stream>>>(DW, nullptr, fc2T, fc2_b, A0, d_out, nullptr);
}